// Round 9
// baseline (881.389 us; speedup 1.0000x reference)
//
#include <hip/hip_runtime.h>
#include <hip/hip_bf16.h>
#include <math.h>

typedef float f32x4 __attribute__((ext_vector_type(4)));
typedef float f32x2 __attribute__((ext_vector_type(2)));
typedef short s16x8 __attribute__((ext_vector_type(8)));
typedef short s16x4 __attribute__((ext_vector_type(4)));
typedef int   i32x4 __attribute__((ext_vector_type(4)));

__device__ __forceinline__ short f2bf(float f) {
  __hip_bfloat16 h = __float2bfloat16(f);
  return __builtin_bit_cast(short, h);
}
__device__ __forceinline__ float bf2f(short s) {
  __hip_bfloat16 h = __builtin_bit_cast(__hip_bfloat16, s);
  return __bfloat162float(h);
}
__device__ __forceinline__ float gelu_f(float x) {
  return 0.5f * x * (1.f + erff(x * 0.70710678118654752440f));
}
__device__ __forceinline__ float waveSum(float v) {
  #pragma unroll
  for (int d = 32; d; d >>= 1) v += __shfl_xor(v, d);
  return v;
}
// Soft barrier: LDS-visibility only; does NOT drain vmcnt.
__device__ __forceinline__ void softBarrier() {
  asm volatile("s_waitcnt lgkmcnt(0)" ::: "memory");
  __builtin_amdgcn_s_barrier();
  asm volatile("" ::: "memory");
}

// ---------------------------------------------------------------------------
// K1: dual LayerNorm over D=128 (qkv_ln and pin_ln) -> bf16 A-matrices
// ---------------------------------------------------------------------------
__global__ __launch_bounds__(256) void ln_dual_k(
    const float* __restrict__ x,
    const float* __restrict__ qg, const float* __restrict__ qb,
    const float* __restrict__ pg, const float* __restrict__ pb,
    short* __restrict__ lnq, short* __restrict__ lnp)
{
  int w = threadIdx.x >> 6, lane = threadIdx.x & 63;
  size_t row = (size_t)blockIdx.x * 4 + w;
  f32x2 v = reinterpret_cast<const f32x2*>(x + row * 128)[lane];
  float s  = v[0] + v[1];
  float sq = v[0]*v[0] + v[1]*v[1];
  s = waveSum(s); sq = waveSum(sq);
  float m = s * (1.f/128.f);
  float rstd = rsqrtf(sq * (1.f/128.f) - m*m + 1e-5f);
  int c = lane * 2;
  float a0 = (v[0]-m)*rstd, a1 = (v[1]-m)*rstd;
  unsigned q0 = (unsigned short)f2bf(a0*qg[c] + qb[c]);
  unsigned q1 = (unsigned short)f2bf(a1*qg[c+1] + qb[c+1]);
  unsigned p0 = (unsigned short)f2bf(a0*pg[c] + pb[c]);
  unsigned p1 = (unsigned short)f2bf(a1*pg[c+1] + pb[c+1]);
  ((unsigned*)lnq)[row*64 + lane] = q0 | (q1 << 16);
  ((unsigned*)lnp)[row*64 + lane] = p0 | (p1 << 16);
}

// ---------------------------------------------------------------------------
// K2: LayerNorm over 256 (attn_ln), fp32 in/out
// ---------------------------------------------------------------------------
__global__ __launch_bounds__(256) void ln256_k(
    const float* __restrict__ in,
    const float* __restrict__ g, const float* __restrict__ bb,
    float* __restrict__ out)
{
  int w = threadIdx.x >> 6, lane = threadIdx.x & 63;
  size_t row = (size_t)blockIdx.x * 4 + w;
  f32x4 v = reinterpret_cast<const f32x4*>(in + row * 256)[lane];
  float s  = v[0]+v[1]+v[2]+v[3];
  float sq = v[0]*v[0]+v[1]*v[1]+v[2]*v[2]+v[3]*v[3];
  s = waveSum(s); sq = waveSum(sq);
  float m = s * (1.f/256.f);
  float rstd = rsqrtf(sq * (1.f/256.f) - m*m + 1e-5f);
  f32x4 g4 = reinterpret_cast<const f32x4*>(g)[lane];
  f32x4 b4 = reinterpret_cast<const f32x4*>(bb)[lane];
  f32x4 o;
  #pragma unroll
  for (int k = 0; k < 4; ++k) o[k] = (v[k]-m)*rstd*g4[k] + b4[k];
  reinterpret_cast<f32x4*>(out + row * 256)[lane] = o;
}

// ---------------------------------------------------------------------------
// K3: LayerNorm over 8192 (mlp_ln) -> bf16
// ---------------------------------------------------------------------------
__global__ __launch_bounds__(256) void ln8192_k(
    const float* __restrict__ x1,
    const float* __restrict__ g, const float* __restrict__ bb,
    short* __restrict__ lnx)
{
  __shared__ float red[8];
  int t = threadIdx.x, w = t >> 6, lane = t & 63;
  int b = blockIdx.x;
  const f32x4* xr = reinterpret_cast<const f32x4*>(x1 + (size_t)b * 8192);
  f32x4 vals[8];
  float s = 0.f, sq = 0.f;
  #pragma unroll
  for (int i = 0; i < 8; ++i) {
    f32x4 v = xr[t + i*256];
    vals[i] = v;
    s  += v[0]+v[1]+v[2]+v[3];
    sq += v[0]*v[0]+v[1]*v[1]+v[2]*v[2]+v[3]*v[3];
  }
  s = waveSum(s); sq = waveSum(sq);
  if (lane == 0) { red[w] = s; red[4+w] = sq; }
  __syncthreads();
  s  = red[0]+red[1]+red[2]+red[3];
  sq = red[4]+red[5]+red[6]+red[7];
  float m = s * (1.f/8192.f);
  float rstd = rsqrtf(sq * (1.f/8192.f) - m*m + 1e-5f);
  #pragma unroll
  for (int i = 0; i < 8; ++i) {
    int idx = (t + i*256) * 4;
    f32x4 g4 = reinterpret_cast<const f32x4*>(g)[t + i*256];
    f32x4 b4 = reinterpret_cast<const f32x4*>(bb)[t + i*256];
    s16x4 o;
    #pragma unroll
    for (int k = 0; k < 4; ++k) o[k] = f2bf((vals[i][k]-m)*rstd*g4[k] + b4[k]);
    *reinterpret_cast<s16x4*>(&lnx[(size_t)b*8192 + idx]) = o;
  }
}

// ---------------------------------------------------------------------------
// Generic bf16-MFMA GEMM for the small GEMMs.
// EPI: 0 = bf16 out (+bias); 1 = f32 out (+bias); 2 = gelu split u/v (pin);
//      3 = f32 out (+bias +res)
// ---------------------------------------------------------------------------
template<int BM, int BN, int WM, int WN, int EPI>
__global__ __launch_bounds__(256) void gemm_k(
    const short* __restrict__ A, const float* __restrict__ Bw,
    const float* __restrict__ bias, const float* __restrict__ res,
    void* __restrict__ O0, void* __restrict__ O1,
    int M, int N, int K, int Nreal, int Kreal)
{
  constexpr int BK = 64;
  __shared__ __align__(16) short As[BM][BK + 8];
  __shared__ __align__(16) short Bs[BN][BK + 8];
  const int t = threadIdx.x;
  const int lane = t & 63;
  const int w = t >> 6;
  const int wm = w / WN, wn = w % WN;
  const int ln15 = lane & 15, hi = lane >> 4;
  const int m0 = blockIdx.y * BM;
  const int n0 = blockIdx.x * BN;

  f32x4 acc[4][4] = {};

  for (int k0 = 0; k0 < K; k0 += BK) {
    #pragma unroll
    for (int i = 0; i < (BM*BK)/(256*8); ++i) {
      int e = (i*256 + t) * 8;
      int r = e / BK, c = e % BK;
      *reinterpret_cast<i32x4*>(&As[r][c]) =
          *reinterpret_cast<const i32x4*>(&A[(size_t)(m0 + r) * K + k0 + c]);
    }
    #pragma unroll
    for (int i = 0; i < (BK*BN)/256; ++i) {
      int idx = i*256 + t;
      int n = idx % BN, k = idx / BN;
      int gk = k0 + k, gn = n0 + n;
      float v = (gk < Kreal && gn < Nreal) ? Bw[(size_t)gk * Nreal + gn] : 0.f;
      Bs[n][k] = f2bf(v);
    }
    __syncthreads();
    #pragma unroll
    for (int kk = 0; kk < BK; kk += 32) {
      s16x8 af[4], bfr[4];
      #pragma unroll
      for (int fm = 0; fm < 4; ++fm)
        af[fm] = *reinterpret_cast<const s16x8*>(&As[wm*64 + fm*16 + ln15][kk + hi*8]);
      #pragma unroll
      for (int fn = 0; fn < 4; ++fn)
        bfr[fn] = *reinterpret_cast<const s16x8*>(&Bs[wn*64 + fn*16 + ln15][kk + hi*8]);
      #pragma unroll
      for (int fm = 0; fm < 4; ++fm)
        #pragma unroll
        for (int fn = 0; fn < 4; ++fn)
          acc[fm][fn] = __builtin_amdgcn_mfma_f32_16x16x32_bf16(
              af[fm], bfr[fn], acc[fm][fn], 0, 0, 0);
    }
    __syncthreads();
  }

  #pragma unroll
  for (int fm = 0; fm < 4; ++fm) {
    #pragma unroll
    for (int fn = 0; fn < 4; ++fn) {
      #pragma unroll
      for (int j = 0; j < 4; ++j) {
        int row = m0 + wm*64 + fm*16 + hi*4 + j;
        int col = n0 + wn*64 + fn*16 + ln15;
        float v = acc[fm][fn][j];
        if constexpr (EPI == 0) {
          v += bias[col];
          ((short*)O0)[(size_t)row * N + col] = f2bf(v);
        } else if constexpr (EPI == 1) {
          v += bias[col];
          ((float*)O0)[(size_t)row * N + col] = v;
        } else if constexpr (EPI == 2) {
          v = gelu_f(v + bias[col]);
          if (col < 256) ((float*)O0)[(size_t)row * 256 + col] = v;
          else ((short*)O1)[(size_t)row * 256 + (col - 256)] = f2bf(v);
        } else { // 3
          v += bias[col] + res[(size_t)row * N + col];
          ((float*)O0)[(size_t)row * N + col] = v;
        }
      }
    }
  }
}

// ---------------------------------------------------------------------------
// Split-K GEMM v8: same pipeline as v7 (A direct global->VGPR, B double-
// buffered LDS w/ XOR swizzle, write-early/load-late, soft barriers), but
// templated on BN and launched with DEEPER SPLIT-K so >= 2 blocks are
// co-resident per CU (VGPR<=128, LDS<=2x32KB). Independent blocks at
// staggered phases overlap each other's B-latency stalls (TLP fix for the
// 17% MfmaUtil / 1.5 TB/s latency-bound signature of R6-R8).
// ---------------------------------------------------------------------------
template<int BN>
__global__ __launch_bounds__(512, 2) void gemm_splitk8(
    const short* __restrict__ A, const float* __restrict__ Bw,
    float* __restrict__ part,
    int N, int K, int Kreal, int ldb, int kchunk, int ntiles)
{
  constexpr int NFR  = BN / 16;        // B fragments per wave
  constexpr int BGRP = 512 / BN;       // thread groups along k
  constexpr int GPT  = 8 / BGRP;       // 8-elem k-granules per thread
  __shared__ __align__(16) short Bs[2][BN * 64];
  const int t = threadIdx.x, lane = t & 63, w = t >> 6;
  const int ln15 = lane & 15, hi = lane >> 4;
  const int nt = blockIdx.x % ntiles, z = blockIdx.x / ntiles;
  const int n0 = nt * BN;
  const int kbeg = z * kchunk;
  const int kend = (kbeg + kchunk < K) ? (kbeg + kchunk) : K;
  const int nsteps = (kend - kbeg) >> 6;

  const int bn = t & (BN - 1);
  const int bg0 = (t / BN) * GPT;
  const bool bok = (n0 + bn) < ldb;
  const int bsw = bn & 7;              // XOR swizzle key

  float br[GPT * 8];
  auto loadB = [&](int k0) {
    #pragma unroll
    for (int g = 0; g < GPT; ++g) {
      const float* bp = Bw + (size_t)(k0 + (bg0 + g) * 8) * ldb + n0 + bn;
      #pragma unroll
      for (int m = 0; m < 8; ++m) {
        int gk = k0 + (bg0 + g) * 8 + m;
        br[g*8 + m] = (bok && gk < Kreal) ? bp[(size_t)m * ldb] : 0.f;
      }
    }
  };
  auto writeB = [&](int buf) {
    short* dst = &Bs[buf][bn * 64];
    #pragma unroll
    for (int g = 0; g < GPT; ++g) {
      s16x8 v;
      #pragma unroll
      for (int m = 0; m < 8; ++m) v[m] = f2bf(br[g*8 + m]);
      *reinterpret_cast<s16x8*>(dst + ((bg0 + g) ^ bsw) * 8) = v;
    }
  };

  f32x4 acc[4][NFR] = {};

  loadB(kbeg);
  writeB(0);
  if (nsteps > 1) loadB(kbeg + 64);
  softBarrier();

  for (int s = 0; s < nsteps; ++s) {
    const int k0 = kbeg + s * 64;
    // A fragments for THIS step (L2-resident)
    s16x8 af[8];
    #pragma unroll
    for (int kk = 0; kk < 2; ++kk)
      #pragma unroll
      for (int fm = 0; fm < 4; ++fm) {
        int row = w * 64 + fm * 16 + ln15;
        af[kk * 4 + fm] = *reinterpret_cast<const s16x8*>(
            &A[(size_t)row * K + k0 + (kk * 4 + hi) * 8]);
      }
    if (s + 1 < nsteps) writeB((s + 1) & 1);
    if (s + 2 < nsteps) loadB(kbeg + (s + 2) * 64);

    const short* bsrc = &Bs[s & 1][0];
    #pragma unroll
    for (int kk = 0; kk < 2; ++kk) {
      const int g = kk * 4 + hi;
      #pragma unroll
      for (int fn = 0; fn < NFR; ++fn) {
        int row = fn * 16 + ln15;
        s16x8 bv = *reinterpret_cast<const s16x8*>(
            &bsrc[row * 64 + ((g ^ (row & 7)) * 8)]);
        #pragma unroll
        for (int fm = 0; fm < 4; ++fm)
          acc[fm][fn] = __builtin_amdgcn_mfma_f32_16x16x32_bf16(
              af[kk * 4 + fm], bv, acc[fm][fn], 0, 0, 0);
      }
    }
    softBarrier();
  }

  #pragma unroll
  for (int fm = 0; fm < 4; ++fm)
    #pragma unroll
    for (int fn = 0; fn < NFR; ++fn)
      #pragma unroll
      for (int j = 0; j < 4; ++j) {
        int row = w * 64 + fm * 16 + hi * 4 + j;
        int col = n0 + fn * 16 + ln15;
        part[((size_t)z * 512 + row) * N + col] = acc[fm][fn][j];
      }
}

// ---------------------------------------------------------------------------
// split-K reduce for mlp1: h3 = gelu(sum_ks part + b1), bf16, col<Nreal guard
// ---------------------------------------------------------------------------
__global__ __launch_bounds__(256) void reduce_mlp1_k(
    const float* __restrict__ part, const float* __restrict__ bias,
    short* __restrict__ h3, int N, int Nreal, int M, int ks)
{
  int col4 = (blockIdx.x * 256 + threadIdx.x) * 4;
  int row = blockIdx.y;
  if (col4 >= N) return;
  size_t base = (size_t)row * N + col4;
  size_t stride = (size_t)M * N;
  f32x4 s = *reinterpret_cast<const f32x4*>(part + base);
  for (int k = 1; k < ks; ++k)
    s += *reinterpret_cast<const f32x4*>(part + base + (size_t)k * stride);
  s16x4 o;
  #pragma unroll
  for (int j = 0; j < 4; ++j) {
    int c = col4 + j;
    float v = 0.f;
    if (c < Nreal) v = gelu_f(s[j] + bias[c]);
    o[j] = f2bf(v);
  }
  *reinterpret_cast<s16x4*>(h3 + base) = o;
}

// ---------------------------------------------------------------------------
// split-K reduce for mlp2: out = sum_ks part + b2 + x1 (f32)
// ---------------------------------------------------------------------------
__global__ __launch_bounds__(256) void reduce_mlp2_k(
    const float* __restrict__ part, const float* __restrict__ bias,
    const float* __restrict__ x1, float* __restrict__ out, int N, int M, int ks)
{
  int col4 = (blockIdx.x * 256 + threadIdx.x) * 4;
  int row = blockIdx.y;
  size_t base = (size_t)row * N + col4;
  size_t stride = (size_t)M * N;
  f32x4 s = *reinterpret_cast<const f32x4*>(part + base);
  for (int k = 1; k < ks; ++k)
    s += *reinterpret_cast<const f32x4*>(part + base + (size_t)k * stride);
  f32x4 b4 = *reinterpret_cast<const f32x4*>(bias + col4);
  f32x4 r4 = *reinterpret_cast<const f32x4*>(x1 + base);
  #pragma unroll
  for (int j = 0; j < 4; ++j) s[j] += b4[j] + r4[j];
  *reinterpret_cast<f32x4*>(out + base) = s;
}

// ---------------------------------------------------------------------------
// K4: fused tiny attention
// ---------------------------------------------------------------------------
__global__ __launch_bounds__(256) void attn_k(
    const short* __restrict__ qkv, const float* __restrict__ relb,
    const float* __restrict__ scale_p, short* __restrict__ av)
{
  __shared__ __align__(16) short qlds[64][136];
  __shared__ __align__(16) short klds[64][136];
  __shared__ __align__(16) short plds[64][72];
  __shared__ __align__(16) short vlds[128][72];
  __shared__ float rb[127];
  int t = threadIdx.x, lane = t & 63, w = t >> 6;
  int ln15 = lane & 15, hi = lane >> 4;
  int b = blockIdx.x;
  if (t < 127) rb[t] = relb[t];

  f32x4 sacc[4] = {};
  for (int kc = 0; kc < 4; ++kc) {
    #pragma unroll
    for (int i = 0; i < 4; ++i) {
      int e = (i*256 + t) * 8;
      int r = e >> 7, c = e & 127;
      size_t base = (size_t)(b*64 + r) * 1536 + kc*128 + c;
      *reinterpret_cast<i32x4*>(&qlds[r][c]) = *reinterpret_cast<const i32x4*>(&qkv[base]);
      *reinterpret_cast<i32x4*>(&klds[r][c]) = *reinterpret_cast<const i32x4*>(&qkv[base + 512]);
    }
    __syncthreads();
    #pragma unroll
    for (int kk = 0; kk < 128; kk += 32) {
      s16x8 aq = *reinterpret_cast<const s16x8*>(&qlds[16*w + ln15][kk + hi*8]);
      #pragma unroll
      for (int fn = 0; fn < 4; ++fn) {
        s16x8 bk = *reinterpret_cast<const s16x8*>(&klds[fn*16 + ln15][kk + hi*8]);
        sacc[fn] = __builtin_amdgcn_mfma_f32_16x16x32_bf16(aq, bk, sacc[fn], 0, 0, 0);
      }
    }
    __syncthreads();
  }

  float scale = scale_p[0];
  #pragma unroll
  for (int j = 0; j < 4; ++j) {
    int row = 16*w + hi*4 + j;
    float pv[4];
    float mx = -1e30f;
    #pragma unroll
    for (int fn = 0; fn < 4; ++fn) {
      int col = fn*16 + ln15;
      pv[fn] = sacc[fn][j] + rb[col - row + 63];
      mx = fmaxf(mx, pv[fn]);
    }
    #pragma unroll
    for (int d = 1; d < 16; d <<= 1) mx = fmaxf(mx, __shfl_xor(mx, d));
    float sum = 0.f;
    #pragma unroll
    for (int fn = 0; fn < 4; ++fn) { pv[fn] = __expf(pv[fn] - mx); sum += pv[fn]; }
    #pragma unroll
    for (int d = 1; d < 16; d <<= 1) sum += __shfl_xor(sum, d);
    float inv = scale / sum;
    #pragma unroll
    for (int fn = 0; fn < 4; ++fn) plds[row][fn*16 + ln15] = f2bf(pv[fn] * inv);
  }
  __syncthreads();

  for (int cc = 0; cc < 4; ++cc) {
    #pragma unroll
    for (int i = 0; i < 8; ++i) {
      int idx = i*256 + t;
      int s = idx >> 5, c4 = (idx & 31) * 4;
      s16x4 vw = *reinterpret_cast<const s16x4*>(
          &qkv[(size_t)(b*64 + s) * 1536 + 1024 + cc*128 + c4]);
      vlds[c4+0][s] = vw[0]; vlds[c4+1][s] = vw[1];
      vlds[c4+2][s] = vw[2]; vlds[c4+3][s] = vw[3];
    }
    __syncthreads();
    f32x4 pacc[8] = {};
    #pragma unroll
    for (int kk = 0; kk < 64; kk += 32) {
      s16x8 ap = *reinterpret_cast<const s16x8*>(&plds[16*w + ln15][kk + hi*8]);
      #pragma unroll
      for (int fn = 0; fn < 8; ++fn) {
        s16x8 bv = *reinterpret_cast<const s16x8*>(&vlds[fn*16 + ln15][kk + hi*8]);
        pacc[fn] = __builtin_amdgcn_mfma_f32_16x16x32_bf16(ap, bv, pacc[fn], 0, 0, 0);
      }
    }
    #pragma unroll
    for (int fn = 0; fn < 8; ++fn)
      #pragma unroll
      for (int j = 0; j < 4; ++j) {
        int row = b*64 + 16*w + hi*4 + j;
        int col = cc*128 + fn*16 + ln15;
        av[(size_t)row * 512 + col] = f2bf(pacc[fn][j]);
      }
    __syncthreads();
  }
}

// ---------------------------------------------------------------------------
// K5: SGU gate
// ---------------------------------------------------------------------------
__global__ __launch_bounds__(256) void gate_k(
    const float* __restrict__ u, const short* __restrict__ vbf,
    const float* __restrict__ a,
    const float* __restrict__ spg_g, const float* __restrict__ spg_b,
    const float* __restrict__ spw, const float* __restrict__ spb,
    const float* __restrict__ pog, const float* __restrict__ pob,
    short* __restrict__ outn)
{
  __shared__ __align__(16) short nvb[256][72];
  __shared__ __align__(16) short spwT[64][72];
  __shared__ float s_spg[64], s_spbl[64], s_spb[64];
  __shared__ float s_pog[256], s_pob[256];
  int t = threadIdx.x, lane = t & 63, w = t >> 6;
  int ln15 = lane & 15, hi = lane >> 4;
  int b = blockIdx.x;

  if (t < 64) { s_spg[t] = spg_g[t]; s_spbl[t] = spg_b[t]; s_spb[t] = spb[t]; }
  s_pog[t] = pog[t]; s_pob[t] = pob[t];
  #pragma unroll
  for (int i = 0; i < 16; ++i) {
    int idx = i*256 + t;
    int sr = idx >> 6, tc = idx & 63;
    spwT[tc][sr] = f2bf(spw[idx]);
  }

  float vvv[64];
  {
    int c = t;
    float s = 0.f, sq = 0.f;
    #pragma unroll
    for (int si = 0; si < 64; ++si) {
      float f = bf2f(vbf[(size_t)(b*64 + si) * 256 + c]);
      vvv[si] = f; s += f; sq += f*f;
    }
    float m = s * (1.f/64.f);
    float rstd = rsqrtf(sq * (1.f/64.f) - m*m + 1e-5f);
    __syncthreads();
    #pragma unroll
    for (int si = 0; si < 64; ++si)
      nvb[c][si] = f2bf((vvv[si]-m)*rstd*s_spg[si] + s_spbl[si]);
  }
  __syncthreads();

  f32x4 yacc[4][4] = {};
  #pragma unroll
  for (int kk = 0; kk < 64; kk += 32) {
    s16x8 af[4], bfr[4];
    #pragma unroll
    for (int fm = 0; fm < 4; ++fm)
      af[fm] = *reinterpret_cast<const s16x8*>(&nvb[64*w + fm*16 + ln15][kk + hi*8]);
    #pragma unroll
    for (int fn = 0; fn < 4; ++fn)
      bfr[fn] = *reinterpret_cast<const s16x8*>(&spwT[fn*16 + ln15][kk + hi*8]);
    #pragma unroll
    for (int fm = 0; fm < 4; ++fm)
      #pragma unroll
      for (int fn = 0; fn < 4; ++fn)
        yacc[fm][fn] = __builtin_amdgcn_mfma_f32_16x16x32_bf16(
            af[fm], bfr[fn], yacc[fm][fn], 0, 0, 0);
  }
  __syncthreads();

  short (*outl)[264] = reinterpret_cast<short(*)[264]>(&nvb[0][0]);
  #pragma unroll
  for (int fm = 0; fm < 4; ++fm) {
    #pragma unroll
    for (int fn = 0; fn < 4; ++fn) {
      int crow = 64*w + fm*16 + hi*4;
      int tcol = fn*16 + ln15;
      f32x4 u4 = *reinterpret_cast<const f32x4*>(&u[(size_t)(b*64 + tcol)*256 + crow]);
      f32x4 a4 = *reinterpret_cast<const f32x4*>(&a[(size_t)(b*64 + tcol)*256 + crow]);
      #pragma unroll
      for (int j = 0; j < 4; ++j) {
        float g = gelu_f(yacc[fm][fn][j] + s_spb[tcol]);
        float o = u4[j] * (g + a4[j]);
        outl[tcol][crow + j] = f2bf(o);
      }
    }
  }
  __syncthreads();

  #pragma unroll
  for (int ri = 0; ri < 16; ++ri) {
    int trow = w*16 + ri;
    int c = lane * 4;
    s16x4 raw = *reinterpret_cast<const s16x4*>(&outl[trow][c]);
    float f0 = bf2f(raw[0]), f1 = bf2f(raw[1]), f2 = bf2f(raw[2]), f3 = bf2f(raw[3]);
    float s  = f0+f1+f2+f3;
    float sq = f0*f0+f1*f1+f2*f2+f3*f3;
    s = waveSum(s); sq = waveSum(sq);
    float m = s * (1.f/256.f);
    float rstd = rsqrtf(sq * (1.f/256.f) - m*m + 1e-5f);
    s16x4 o;
    o[0] = f2bf((f0-m)*rstd*s_pog[c+0] + s_pob[c+0]);
    o[1] = f2bf((f1-m)*rstd*s_pog[c+1] + s_pob[c+1]);
    o[2] = f2bf((f2-m)*rstd*s_pog[c+2] + s_pob[c+2]);
    o[3] = f2bf((f3-m)*rstd*s_pog[c+3] + s_pob[c+3]);
    *reinterpret_cast<s16x4*>(&outn[(size_t)(b*64 + trow)*256 + c]) = o;
  }
}

// ---------------------------------------------------------------------------
extern "C" void kernel_launch(void* const* d_in, const int* in_sizes, int n_in,
                              void* d_out, int out_size, void* d_ws, size_t ws_size,
                              hipStream_t stream)
{
  const float* x          = (const float*)d_in[0];
  const float* qkv_ln_g   = (const float*)d_in[1];
  const float* qkv_ln_b   = (const float*)d_in[2];
  const float* qkv_w      = (const float*)d_in[3];
  const float* qkv_b      = (const float*)d_in[4];
  const float* attn_pw    = (const float*)d_in[5];
  const float* attn_pb    = (const float*)d_in[6];
  const float* attn_ln_g  = (const float*)d_in[7];
  const float* attn_ln_b  = (const float*)d_in[8];
  const float* rel_bias   = (const float*)d_in[9];
  const float* scale      = (const float*)d_in[10];
  const float* pin_ln_g   = (const float*)d_in[11];
  const float* pin_ln_b   = (const float*)d_in[12];
  const float* pin_w      = (const float*)d_in[13];
  const float* pin_b      = (const float*)d_in[14];
  const float* sp_ln_g    = (const float*)d_in[15];
  const float* sp_ln_b    = (const float*)d_in[16];
  const float* sp_w       = (const float*)d_in[17];
  const float* sp_b       = (const float*)d_in[18];
  const float* pout_ln_g  = (const float*)d_in[19];
  const float* pout_ln_b  = (const float*)d_in[20];
  const float* pout_w     = (const float*)d_in[21];
  const float* pout_b     = (const float*)d_in[22];
  const float* mlp_ln_g   = (const float*)d_in[23];
  const float* mlp_ln_b   = (const float*)d_in[24];
  const float* mlp_w1     = (const float*)d_in[25];
  const float* mlp_b1     = (const float*)d_in[26];
  const float* mlp_w2     = (const float*)d_in[27];
  const float* mlp_b2     = (const float*)d_in[28];

  char* ws = (char*)d_ws;
  short* lnq  = (short*)(ws + 0);            // 8.39 MB
  short* lnp  = (short*)(ws + 8388608);      // 8.39 MB
  short* qkvb = (short*)(ws + 16777216);     // 100.7 MB (dead after attn)
  short* avb  = (short*)(ws + 117440512);    // 33.6 MB
  float* projb= (float*)(ws + 16777216);     // alias qkv region
  float* ab   = (float*)(ws + 50331648);     // alias qkv region
  float* ub   = (float*)(ws + 83886080);     // alias qkv region
  short* vbfb = (short*)(ws + 117440512);    // alias av region
  short* outnb= (short*)(ws + 134217728);    // alias av region
  float* x1b  = (float*)(ws + 0);            // alias lnq/lnp region [0,16.8MB)
  short* lnxb = (short*)(ws + 150994944);    // 8.39 MB
  short* h3b  = (short*)(ws + 159383552);    // 9.31 MB (512 x 9088, pad zeroed)
  float* partb= (float*)(ws + 16777216);     // split-K partials, region =
                                             // [16.78, 150.99) MB = 134.2 MB

  ln_dual_k<<<8192, 256, 0, stream>>>(x, qkv_ln_g, qkv_ln_b, pin_ln_g, pin_ln_b, lnq, lnp);
  gemm_k<128,128,2,2,0><<<dim3(12,256), 256, 0, stream>>>(
      lnq, qkv_w, qkv_b, nullptr, qkvb, nullptr, 32768, 1536, 128, 1536, 128);
  attn_k<<<512, 256, 0, stream>>>(qkvb, rel_bias, scale, avb);
  gemm_k<128,128,2,2,1><<<dim3(2,256), 256, 0, stream>>>(
      avb, attn_pw, attn_pb, nullptr, projb, nullptr, 32768, 256, 512, 256, 512);
  ln256_k<<<8192, 256, 0, stream>>>(projb, attn_ln_g, attn_ln_b, ab);
  gemm_k<128,128,2,2,2><<<dim3(4,256), 256, 0, stream>>>(
      lnp, pin_w, pin_b, nullptr, ub, vbfb, 32768, 512, 128, 512, 128);
  gate_k<<<512, 256, 0, stream>>>(ub, vbfb, ab, sp_ln_g, sp_ln_b, sp_w, sp_b,
                                  pout_ln_g, pout_ln_b, outnb);
  gemm_k<128,128,2,2,3><<<dim3(1,256), 256, 0, stream>>>(
      outnb, pout_w, pout_b, x, x1b, nullptr, 32768, 128, 256, 128, 256);
  ln8192_k<<<512, 256, 0, stream>>>(x1b, mlp_ln_g, mlp_ln_b, lnxb);

  // mlp1: [512,8192] @ [8192,9011] (N padded 9088 = 142*64), BN=64,
  // split-K 7 -> 994 blocks (~4/CU, 2 co-resident). part = 130.4 MB.
  // kchunk 1216 = 19 steps (x6), last chunk 896 = 14 steps.
  gemm_splitk8<64><<<994, 512, 0, stream>>>(
      lnxb, mlp_w1, partb, /*N=*/9088, /*K=*/8192, /*Kreal=*/8192,
      /*ldb=*/9011, /*kchunk=*/1216, /*ntiles=*/142);
  reduce_mlp1_k<<<dim3(9, 512), 256, 0, stream>>>(partb, mlp_b1, h3b, 9088, 9011, 512, 7);

  // mlp2: [512,9088] @ [9011,8192], BN=128, split-K 8 -> 512 blocks =
  // exactly 2/CU co-resident. part = 134.2 MB (exactly fits region).
  // kchunk 1152 = 18 steps (x7), last chunk 1024 = 16 steps.
  gemm_splitk8<128><<<512, 512, 0, stream>>>(
      h3b, mlp_w2, partb, /*N=*/8192, /*K=*/9088, /*Kreal=*/9011,
      /*ldb=*/8192, /*kchunk=*/1152, /*ntiles=*/64);
  reduce_mlp2_k<<<dim3(8, 512), 256, 0, stream>>>(partb, mlp_b2, x1b, (float*)d_out, 8192, 512, 8);
}

// Round 10
// 769.157 us; speedup vs baseline: 1.1459x; 1.1459x over previous
//
#include <hip/hip_runtime.h>
#include <hip/hip_bf16.h>
#include <math.h>

typedef float f32x4 __attribute__((ext_vector_type(4)));
typedef float f32x2 __attribute__((ext_vector_type(2)));
typedef short s16x8 __attribute__((ext_vector_type(8)));
typedef short s16x4 __attribute__((ext_vector_type(4)));
typedef int   i32x4 __attribute__((ext_vector_type(4)));

__device__ __forceinline__ short f2bf(float f) {
  __hip_bfloat16 h = __float2bfloat16(f);
  return __builtin_bit_cast(short, h);
}
__device__ __forceinline__ float bf2f(short s) {
  __hip_bfloat16 h = __builtin_bit_cast(__hip_bfloat16, s);
  return __bfloat162float(h);
}
__device__ __forceinline__ float gelu_f(float x) {
  return 0.5f * x * (1.f + erff(x * 0.70710678118654752440f));
}
__device__ __forceinline__ float waveSum(float v) {
  #pragma unroll
  for (int d = 32; d; d >>= 1) v += __shfl_xor(v, d);
  return v;
}
// Soft barrier: LDS-visibility only; does NOT drain vmcnt.
__device__ __forceinline__ void softBarrier() {
  asm volatile("s_waitcnt lgkmcnt(0)" ::: "memory");
  __builtin_amdgcn_s_barrier();
  asm volatile("" ::: "memory");
}

// ---------------------------------------------------------------------------
// K1: dual LayerNorm over D=128 (qkv_ln and pin_ln) -> bf16 A-matrices
// ---------------------------------------------------------------------------
__global__ __launch_bounds__(256) void ln_dual_k(
    const float* __restrict__ x,
    const float* __restrict__ qg, const float* __restrict__ qb,
    const float* __restrict__ pg, const float* __restrict__ pb,
    short* __restrict__ lnq, short* __restrict__ lnp)
{
  int w = threadIdx.x >> 6, lane = threadIdx.x & 63;
  size_t row = (size_t)blockIdx.x * 4 + w;
  f32x2 v = reinterpret_cast<const f32x2*>(x + row * 128)[lane];
  float s  = v[0] + v[1];
  float sq = v[0]*v[0] + v[1]*v[1];
  s = waveSum(s); sq = waveSum(sq);
  float m = s * (1.f/128.f);
  float rstd = rsqrtf(sq * (1.f/128.f) - m*m + 1e-5f);
  int c = lane * 2;
  float a0 = (v[0]-m)*rstd, a1 = (v[1]-m)*rstd;
  unsigned q0 = (unsigned short)f2bf(a0*qg[c] + qb[c]);
  unsigned q1 = (unsigned short)f2bf(a1*qg[c+1] + qb[c+1]);
  unsigned p0 = (unsigned short)f2bf(a0*pg[c] + pb[c]);
  unsigned p1 = (unsigned short)f2bf(a1*pg[c+1] + pb[c+1]);
  ((unsigned*)lnq)[row*64 + lane] = q0 | (q1 << 16);
  ((unsigned*)lnp)[row*64 + lane] = p0 | (p1 << 16);
}

// ---------------------------------------------------------------------------
// K2: LayerNorm over 256 (attn_ln), fp32 in/out
// ---------------------------------------------------------------------------
__global__ __launch_bounds__(256) void ln256_k(
    const float* __restrict__ in,
    const float* __restrict__ g, const float* __restrict__ bb,
    float* __restrict__ out)
{
  int w = threadIdx.x >> 6, lane = threadIdx.x & 63;
  size_t row = (size_t)blockIdx.x * 4 + w;
  f32x4 v = reinterpret_cast<const f32x4*>(in + row * 256)[lane];
  float s  = v[0]+v[1]+v[2]+v[3];
  float sq = v[0]*v[0]+v[1]*v[1]+v[2]*v[2]+v[3]*v[3];
  s = waveSum(s); sq = waveSum(sq);
  float m = s * (1.f/256.f);
  float rstd = rsqrtf(sq * (1.f/256.f) - m*m + 1e-5f);
  f32x4 g4 = reinterpret_cast<const f32x4*>(g)[lane];
  f32x4 b4 = reinterpret_cast<const f32x4*>(bb)[lane];
  f32x4 o;
  #pragma unroll
  for (int k = 0; k < 4; ++k) o[k] = (v[k]-m)*rstd*g4[k] + b4[k];
  reinterpret_cast<f32x4*>(out + row * 256)[lane] = o;
}

// ---------------------------------------------------------------------------
// K3: LayerNorm over 8192 (mlp_ln) -> bf16, TILE-PACKED output:
// lnxp[(idx/64)*512 + board][idx%64]  (A'[kt][row][64] layout for splitk)
// ---------------------------------------------------------------------------
__global__ __launch_bounds__(256) void ln8192_k(
    const float* __restrict__ x1,
    const float* __restrict__ g, const float* __restrict__ bb,
    short* __restrict__ lnxp)
{
  __shared__ float red[8];
  int t = threadIdx.x, w = t >> 6, lane = t & 63;
  int b = blockIdx.x;
  const f32x4* xr = reinterpret_cast<const f32x4*>(x1 + (size_t)b * 8192);
  f32x4 vals[8];
  float s = 0.f, sq = 0.f;
  #pragma unroll
  for (int i = 0; i < 8; ++i) {
    f32x4 v = xr[t + i*256];
    vals[i] = v;
    s  += v[0]+v[1]+v[2]+v[3];
    sq += v[0]*v[0]+v[1]*v[1]+v[2]*v[2]+v[3]*v[3];
  }
  s = waveSum(s); sq = waveSum(sq);
  if (lane == 0) { red[w] = s; red[4+w] = sq; }
  __syncthreads();
  s  = red[0]+red[1]+red[2]+red[3];
  sq = red[4]+red[5]+red[6]+red[7];
  float m = s * (1.f/8192.f);
  float rstd = rsqrtf(sq * (1.f/8192.f) - m*m + 1e-5f);
  #pragma unroll
  for (int i = 0; i < 8; ++i) {
    int idx = (t + i*256) * 4;
    f32x4 g4 = reinterpret_cast<const f32x4*>(g)[t + i*256];
    f32x4 b4 = reinterpret_cast<const f32x4*>(bb)[t + i*256];
    s16x4 o;
    #pragma unroll
    for (int k = 0; k < 4; ++k) o[k] = f2bf((vals[i][k]-m)*rstd*g4[k] + b4[k]);
    size_t paddr = ((size_t)(idx >> 6) * 512 + b) * 64 + (idx & 63);
    *reinterpret_cast<s16x4*>(&lnxp[paddr]) = o;
  }
}

// ---------------------------------------------------------------------------
// Generic bf16-MFMA GEMM for the small GEMMs.
// EPI: 0 = bf16 out (+bias); 1 = f32 out (+bias); 2 = gelu split u/v (pin);
//      3 = f32 out (+bias +res)
// ---------------------------------------------------------------------------
template<int BM, int BN, int WM, int WN, int EPI>
__global__ __launch_bounds__(256) void gemm_k(
    const short* __restrict__ A, const float* __restrict__ Bw,
    const float* __restrict__ bias, const float* __restrict__ res,
    void* __restrict__ O0, void* __restrict__ O1,
    int M, int N, int K, int Nreal, int Kreal)
{
  constexpr int BK = 64;
  __shared__ __align__(16) short As[BM][BK + 8];
  __shared__ __align__(16) short Bs[BN][BK + 8];
  const int t = threadIdx.x;
  const int lane = t & 63;
  const int w = t >> 6;
  const int wm = w / WN, wn = w % WN;
  const int ln15 = lane & 15, hi = lane >> 4;
  const int m0 = blockIdx.y * BM;
  const int n0 = blockIdx.x * BN;

  f32x4 acc[4][4] = {};

  for (int k0 = 0; k0 < K; k0 += BK) {
    #pragma unroll
    for (int i = 0; i < (BM*BK)/(256*8); ++i) {
      int e = (i*256 + t) * 8;
      int r = e / BK, c = e % BK;
      *reinterpret_cast<i32x4*>(&As[r][c]) =
          *reinterpret_cast<const i32x4*>(&A[(size_t)(m0 + r) * K + k0 + c]);
    }
    #pragma unroll
    for (int i = 0; i < (BK*BN)/256; ++i) {
      int idx = i*256 + t;
      int n = idx % BN, k = idx / BN;
      int gk = k0 + k, gn = n0 + n;
      float v = (gk < Kreal && gn < Nreal) ? Bw[(size_t)gk * Nreal + gn] : 0.f;
      Bs[n][k] = f2bf(v);
    }
    __syncthreads();
    #pragma unroll
    for (int kk = 0; kk < BK; kk += 32) {
      s16x8 af[4], bfr[4];
      #pragma unroll
      for (int fm = 0; fm < 4; ++fm)
        af[fm] = *reinterpret_cast<const s16x8*>(&As[wm*64 + fm*16 + ln15][kk + hi*8]);
      #pragma unroll
      for (int fn = 0; fn < 4; ++fn)
        bfr[fn] = *reinterpret_cast<const s16x8*>(&Bs[wn*64 + fn*16 + ln15][kk + hi*8]);
      #pragma unroll
      for (int fm = 0; fm < 4; ++fm)
        #pragma unroll
        for (int fn = 0; fn < 4; ++fn)
          acc[fm][fn] = __builtin_amdgcn_mfma_f32_16x16x32_bf16(
              af[fm], bfr[fn], acc[fm][fn], 0, 0, 0);
    }
    __syncthreads();
  }

  #pragma unroll
  for (int fm = 0; fm < 4; ++fm) {
    #pragma unroll
    for (int fn = 0; fn < 4; ++fn) {
      #pragma unroll
      for (int j = 0; j < 4; ++j) {
        int row = m0 + wm*64 + fm*16 + hi*4 + j;
        int col = n0 + wn*64 + fn*16 + ln15;
        float v = acc[fm][fn][j];
        if constexpr (EPI == 0) {
          v += bias[col];
          ((short*)O0)[(size_t)row * N + col] = f2bf(v);
        } else if constexpr (EPI == 1) {
          v += bias[col];
          ((float*)O0)[(size_t)row * N + col] = v;
        } else if constexpr (EPI == 2) {
          v = gelu_f(v + bias[col]);
          if (col < 256) ((float*)O0)[(size_t)row * 256 + col] = v;
          else ((short*)O1)[(size_t)row * 256 + (col - 256)] = f2bf(v);
        } else { // 3
          v += bias[col] + res[(size_t)row * N + col];
          ((float*)O0)[(size_t)row * N + col] = v;
        }
      }
    }
  }
}

// ---------------------------------------------------------------------------
// Split-K GEMM v9: R7 pipeline (BM=512, BN=128, BK=64, 8 waves, B double-
// buffered LDS w/ XOR swizzle, write-early/load-late, soft barriers), with
// ONE change: A is TILE-PACKED A'[k/64][512][64]. The old row-major A had
// row-stride 16KB/18KB (power-of-2): every A-frag load scattered 16 segments
// whose addresses differ only in high bits -> same L2 set/channel ->
// serialized drain (the 3x step-time gap of R6-R9). Packed tiles are
// contiguous 2KB regions: no aliasing, stream-friendly.
// ---------------------------------------------------------------------------
__global__ __launch_bounds__(512, 2) void gemm_splitk9(
    const short* __restrict__ Ap, const float* __restrict__ Bw,
    float* __restrict__ part,
    int N, int K, int Kreal, int ldb, int kchunk, int ntiles)
{
  __shared__ __align__(16) short Bs[2][128 * 64];  // 2 x 16 KB
  const int t = threadIdx.x, lane = t & 63, w = t >> 6;
  const int ln15 = lane & 15, hi = lane >> 4;
  const int nt = blockIdx.x % ntiles, z = blockIdx.x / ntiles;
  const int n0 = nt * 128;
  const int kbeg = z * kchunk;
  const int kend = (kbeg + kchunk < K) ? (kbeg + kchunk) : K;
  const int nsteps = (kend - kbeg) >> 6;

  const int bn = t & 127;
  const int bg0 = (t >> 7) * 2;
  const bool bok = (n0 + bn) < ldb;
  const int bsw = bn & 7;                    // XOR swizzle key

  float br[16];
  auto loadB = [&](int k0) {
    const float* bp = Bw + (size_t)(k0 + bg0 * 8) * ldb + n0 + bn;
    #pragma unroll
    for (int m = 0; m < 16; ++m) {
      int gk = k0 + bg0 * 8 + m;
      br[m] = (bok && gk < Kreal) ? bp[(size_t)m * ldb] : 0.f;
    }
  };
  auto writeB = [&](int buf) {
    s16x8 v0, v1;
    #pragma unroll
    for (int m = 0; m < 8; ++m) { v0[m] = f2bf(br[m]); v1[m] = f2bf(br[8 + m]); }
    short* dst = &Bs[buf][bn * 64];
    *reinterpret_cast<s16x8*>(dst + ((bg0    ) ^ bsw) * 8) = v0;
    *reinterpret_cast<s16x8*>(dst + ((bg0 + 1) ^ bsw) * 8) = v1;
  };

  f32x4 acc[4][8] = {};

  loadB(kbeg);
  writeB(0);
  if (nsteps > 1) loadB(kbeg + 64);
  softBarrier();

  for (int s = 0; s < nsteps; ++s) {
    const int k0 = kbeg + s * 64;
    // A fragments for THIS step, from the packed 2KB tiles
    const short* atile = Ap + (size_t)(k0 >> 6) * 512 * 64;
    s16x8 af[8];
    #pragma unroll
    for (int kk = 0; kk < 2; ++kk)
      #pragma unroll
      for (int fm = 0; fm < 4; ++fm) {
        int row = w * 64 + fm * 16 + ln15;
        af[kk * 4 + fm] = *reinterpret_cast<const s16x8*>(
            &atile[row * 64 + (kk * 4 + hi) * 8]);
      }
    if (s + 1 < nsteps) writeB((s + 1) & 1);
    if (s + 2 < nsteps) loadB(kbeg + (s + 2) * 64);

    const short* bsrc = &Bs[s & 1][0];
    #pragma unroll
    for (int kk = 0; kk < 2; ++kk) {
      const int g = kk * 4 + hi;
      #pragma unroll
      for (int fn = 0; fn < 8; ++fn) {
        int row = fn * 16 + ln15;
        s16x8 bv = *reinterpret_cast<const s16x8*>(
            &bsrc[row * 64 + ((g ^ (row & 7)) * 8)]);
        #pragma unroll
        for (int fm = 0; fm < 4; ++fm)
          acc[fm][fn] = __builtin_amdgcn_mfma_f32_16x16x32_bf16(
              af[kk * 4 + fm], bv, acc[fm][fn], 0, 0, 0);
      }
    }
    softBarrier();
  }

  #pragma unroll
  for (int fm = 0; fm < 4; ++fm)
    #pragma unroll
    for (int fn = 0; fn < 8; ++fn)
      #pragma unroll
      for (int j = 0; j < 4; ++j) {
        int row = w * 64 + fm * 16 + hi * 4 + j;
        int col = n0 + fn * 16 + ln15;
        part[((size_t)z * 512 + row) * N + col] = acc[fm][fn][j];
      }
}

// ---------------------------------------------------------------------------
// split-K reduce for mlp1: h3 = gelu(sum_ks part + b1), bf16, col<Nreal guard
// TILE-PACKED output: h3p[(col/64)*512 + row][col%64]
// ---------------------------------------------------------------------------
__global__ __launch_bounds__(256) void reduce_mlp1_k(
    const float* __restrict__ part, const float* __restrict__ bias,
    short* __restrict__ h3p, int N, int Nreal, int M, int ks)
{
  int col4 = (blockIdx.x * 256 + threadIdx.x) * 4;
  int row = blockIdx.y;
  if (col4 >= N) return;
  size_t base = (size_t)row * N + col4;
  size_t stride = (size_t)M * N;
  f32x4 s = *reinterpret_cast<const f32x4*>(part + base);
  for (int k = 1; k < ks; ++k)
    s += *reinterpret_cast<const f32x4*>(part + base + (size_t)k * stride);
  s16x4 o;
  #pragma unroll
  for (int j = 0; j < 4; ++j) {
    int c = col4 + j;
    float v = 0.f;
    if (c < Nreal) v = gelu_f(s[j] + bias[c]);
    o[j] = f2bf(v);
  }
  size_t paddr = ((size_t)(col4 >> 6) * 512 + row) * 64 + (col4 & 63);
  *reinterpret_cast<s16x4*>(&h3p[paddr]) = o;
}

// ---------------------------------------------------------------------------
// split-K reduce for mlp2: out = sum_ks part + b2 + x1 (f32)
// ---------------------------------------------------------------------------
__global__ __launch_bounds__(256) void reduce_mlp2_k(
    const float* __restrict__ part, const float* __restrict__ bias,
    const float* __restrict__ x1, float* __restrict__ out, int N, int M, int ks)
{
  int col4 = (blockIdx.x * 256 + threadIdx.x) * 4;
  int row = blockIdx.y;
  size_t base = (size_t)row * N + col4;
  size_t stride = (size_t)M * N;
  f32x4 s = *reinterpret_cast<const f32x4*>(part + base);
  for (int k = 1; k < ks; ++k)
    s += *reinterpret_cast<const f32x4*>(part + base + (size_t)k * stride);
  f32x4 b4 = *reinterpret_cast<const f32x4*>(bias + col4);
  f32x4 r4 = *reinterpret_cast<const f32x4*>(x1 + base);
  #pragma unroll
  for (int j = 0; j < 4; ++j) s[j] += b4[j] + r4[j];
  *reinterpret_cast<f32x4*>(out + base) = s;
}

// ---------------------------------------------------------------------------
// K4: fused tiny attention
// ---------------------------------------------------------------------------
__global__ __launch_bounds__(256) void attn_k(
    const short* __restrict__ qkv, const float* __restrict__ relb,
    const float* __restrict__ scale_p, short* __restrict__ av)
{
  __shared__ __align__(16) short qlds[64][136];
  __shared__ __align__(16) short klds[64][136];
  __shared__ __align__(16) short plds[64][72];
  __shared__ __align__(16) short vlds[128][72];
  __shared__ float rb[127];
  int t = threadIdx.x, lane = t & 63, w = t >> 6;
  int ln15 = lane & 15, hi = lane >> 4;
  int b = blockIdx.x;
  if (t < 127) rb[t] = relb[t];

  f32x4 sacc[4] = {};
  for (int kc = 0; kc < 4; ++kc) {
    #pragma unroll
    for (int i = 0; i < 4; ++i) {
      int e = (i*256 + t) * 8;
      int r = e >> 7, c = e & 127;
      size_t base = (size_t)(b*64 + r) * 1536 + kc*128 + c;
      *reinterpret_cast<i32x4*>(&qlds[r][c]) = *reinterpret_cast<const i32x4*>(&qkv[base]);
      *reinterpret_cast<i32x4*>(&klds[r][c]) = *reinterpret_cast<const i32x4*>(&qkv[base + 512]);
    }
    __syncthreads();
    #pragma unroll
    for (int kk = 0; kk < 128; kk += 32) {
      s16x8 aq = *reinterpret_cast<const s16x8*>(&qlds[16*w + ln15][kk + hi*8]);
      #pragma unroll
      for (int fn = 0; fn < 4; ++fn) {
        s16x8 bk = *reinterpret_cast<const s16x8*>(&klds[fn*16 + ln15][kk + hi*8]);
        sacc[fn] = __builtin_amdgcn_mfma_f32_16x16x32_bf16(aq, bk, sacc[fn], 0, 0, 0);
      }
    }
    __syncthreads();
  }

  float scale = scale_p[0];
  #pragma unroll
  for (int j = 0; j < 4; ++j) {
    int row = 16*w + hi*4 + j;
    float pv[4];
    float mx = -1e30f;
    #pragma unroll
    for (int fn = 0; fn < 4; ++fn) {
      int col = fn*16 + ln15;
      pv[fn] = sacc[fn][j] + rb[col - row + 63];
      mx = fmaxf(mx, pv[fn]);
    }
    #pragma unroll
    for (int d = 1; d < 16; d <<= 1) mx = fmaxf(mx, __shfl_xor(mx, d));
    float sum = 0.f;
    #pragma unroll
    for (int fn = 0; fn < 4; ++fn) { pv[fn] = __expf(pv[fn] - mx); sum += pv[fn]; }
    #pragma unroll
    for (int d = 1; d < 16; d <<= 1) sum += __shfl_xor(sum, d);
    float inv = scale / sum;
    #pragma unroll
    for (int fn = 0; fn < 4; ++fn) plds[row][fn*16 + ln15] = f2bf(pv[fn] * inv);
  }
  __syncthreads();

  for (int cc = 0; cc < 4; ++cc) {
    #pragma unroll
    for (int i = 0; i < 8; ++i) {
      int idx = i*256 + t;
      int s = idx >> 5, c4 = (idx & 31) * 4;
      s16x4 vw = *reinterpret_cast<const s16x4*>(
          &qkv[(size_t)(b*64 + s) * 1536 + 1024 + cc*128 + c4]);
      vlds[c4+0][s] = vw[0]; vlds[c4+1][s] = vw[1];
      vlds[c4+2][s] = vw[2]; vlds[c4+3][s] = vw[3];
    }
    __syncthreads();
    f32x4 pacc[8] = {};
    #pragma unroll
    for (int kk = 0; kk < 64; kk += 32) {
      s16x8 ap = *reinterpret_cast<const s16x8*>(&plds[16*w + ln15][kk + hi*8]);
      #pragma unroll
      for (int fn = 0; fn < 8; ++fn) {
        s16x8 bv = *reinterpret_cast<const s16x8*>(&vlds[fn*16 + ln15][kk + hi*8]);
        pacc[fn] = __builtin_amdgcn_mfma_f32_16x16x32_bf16(ap, bv, pacc[fn], 0, 0, 0);
      }
    }
    #pragma unroll
    for (int fn = 0; fn < 8; ++fn)
      #pragma unroll
      for (int j = 0; j < 4; ++j) {
        int row = b*64 + 16*w + hi*4 + j;
        int col = cc*128 + fn*16 + ln15;
        av[(size_t)row * 512 + col] = f2bf(pacc[fn][j]);
      }
    __syncthreads();
  }
}

// ---------------------------------------------------------------------------
// K5: SGU gate
// ---------------------------------------------------------------------------
__global__ __launch_bounds__(256) void gate_k(
    const float* __restrict__ u, const short* __restrict__ vbf,
    const float* __restrict__ a,
    const float* __restrict__ spg_g, const float* __restrict__ spg_b,
    const float* __restrict__ spw, const float* __restrict__ spb,
    const float* __restrict__ pog, const float* __restrict__ pob,
    short* __restrict__ outn)
{
  __shared__ __align__(16) short nvb[256][72];
  __shared__ __align__(16) short spwT[64][72];
  __shared__ float s_spg[64], s_spbl[64], s_spb[64];
  __shared__ float s_pog[256], s_pob[256];
  int t = threadIdx.x, lane = t & 63, w = t >> 6;
  int ln15 = lane & 15, hi = lane >> 4;
  int b = blockIdx.x;

  if (t < 64) { s_spg[t] = spg_g[t]; s_spbl[t] = spg_b[t]; s_spb[t] = spb[t]; }
  s_pog[t] = pog[t]; s_pob[t] = pob[t];
  #pragma unroll
  for (int i = 0; i < 16; ++i) {
    int idx = i*256 + t;
    int sr = idx >> 6, tc = idx & 63;
    spwT[tc][sr] = f2bf(spw[idx]);
  }

  float vvv[64];
  {
    int c = t;
    float s = 0.f, sq = 0.f;
    #pragma unroll
    for (int si = 0; si < 64; ++si) {
      float f = bf2f(vbf[(size_t)(b*64 + si) * 256 + c]);
      vvv[si] = f; s += f; sq += f*f;
    }
    float m = s * (1.f/64.f);
    float rstd = rsqrtf(sq * (1.f/64.f) - m*m + 1e-5f);
    __syncthreads();
    #pragma unroll
    for (int si = 0; si < 64; ++si)
      nvb[c][si] = f2bf((vvv[si]-m)*rstd*s_spg[si] + s_spbl[si]);
  }
  __syncthreads();

  f32x4 yacc[4][4] = {};
  #pragma unroll
  for (int kk = 0; kk < 64; kk += 32) {
    s16x8 af[4], bfr[4];
    #pragma unroll
    for (int fm = 0; fm < 4; ++fm)
      af[fm] = *reinterpret_cast<const s16x8*>(&nvb[64*w + fm*16 + ln15][kk + hi*8]);
    #pragma unroll
    for (int fn = 0; fn < 4; ++fn)
      bfr[fn] = *reinterpret_cast<const s16x8*>(&spwT[fn*16 + ln15][kk + hi*8]);
    #pragma unroll
    for (int fm = 0; fm < 4; ++fm)
      #pragma unroll
      for (int fn = 0; fn < 4; ++fn)
        yacc[fm][fn] = __builtin_amdgcn_mfma_f32_16x16x32_bf16(
            af[fm], bfr[fn], yacc[fm][fn], 0, 0, 0);
  }
  __syncthreads();

  short (*outl)[264] = reinterpret_cast<short(*)[264]>(&nvb[0][0]);
  #pragma unroll
  for (int fm = 0; fm < 4; ++fm) {
    #pragma unroll
    for (int fn = 0; fn < 4; ++fn) {
      int crow = 64*w + fm*16 + hi*4;
      int tcol = fn*16 + ln15;
      f32x4 u4 = *reinterpret_cast<const f32x4*>(&u[(size_t)(b*64 + tcol)*256 + crow]);
      f32x4 a4 = *reinterpret_cast<const f32x4*>(&a[(size_t)(b*64 + tcol)*256 + crow]);
      #pragma unroll
      for (int j = 0; j < 4; ++j) {
        float g = gelu_f(yacc[fm][fn][j] + s_spb[tcol]);
        float o = u4[j] * (g + a4[j]);
        outl[tcol][crow + j] = f2bf(o);
      }
    }
  }
  __syncthreads();

  #pragma unroll
  for (int ri = 0; ri < 16; ++ri) {
    int trow = w*16 + ri;
    int c = lane * 4;
    s16x4 raw = *reinterpret_cast<const s16x4*>(&outl[trow][c]);
    float f0 = bf2f(raw[0]), f1 = bf2f(raw[1]), f2 = bf2f(raw[2]), f3 = bf2f(raw[3]);
    float s  = f0+f1+f2+f3;
    float sq = f0*f0+f1*f1+f2*f2+f3*f3;
    s = waveSum(s); sq = waveSum(sq);
    float m = s * (1.f/256.f);
    float rstd = rsqrtf(sq * (1.f/256.f) - m*m + 1e-5f);
    s16x4 o;
    o[0] = f2bf((f0-m)*rstd*s_pog[c+0] + s_pob[c+0]);
    o[1] = f2bf((f1-m)*rstd*s_pog[c+1] + s_pob[c+1]);
    o[2] = f2bf((f2-m)*rstd*s_pog[c+2] + s_pob[c+2]);
    o[3] = f2bf((f3-m)*rstd*s_pog[c+3] + s_pob[c+3]);
    *reinterpret_cast<s16x4*>(&outn[(size_t)(b*64 + trow)*256 + c]) = o;
  }
}

// ---------------------------------------------------------------------------
extern "C" void kernel_launch(void* const* d_in, const int* in_sizes, int n_in,
                              void* d_out, int out_size, void* d_ws, size_t ws_size,
                              hipStream_t stream)
{
  const float* x          = (const float*)d_in[0];
  const float* qkv_ln_g   = (const float*)d_in[1];
  const float* qkv_ln_b   = (const float*)d_in[2];
  const float* qkv_w      = (const float*)d_in[3];
  const float* qkv_b      = (const float*)d_in[4];
  const float* attn_pw    = (const float*)d_in[5];
  const float* attn_pb    = (const float*)d_in[6];
  const float* attn_ln_g  = (const float*)d_in[7];
  const float* attn_ln_b  = (const float*)d_in[8];
  const float* rel_bias   = (const float*)d_in[9];
  const float* scale      = (const float*)d_in[10];
  const float* pin_ln_g   = (const float*)d_in[11];
  const float* pin_ln_b   = (const float*)d_in[12];
  const float* pin_w      = (const float*)d_in[13];
  const float* pin_b      = (const float*)d_in[14];
  const float* sp_ln_g    = (const float*)d_in[15];
  const float* sp_ln_b    = (const float*)d_in[16];
  const float* sp_w       = (const float*)d_in[17];
  const float* sp_b       = (const float*)d_in[18];
  const float* pout_ln_g  = (const float*)d_in[19];
  const float* pout_ln_b  = (const float*)d_in[20];
  const float* pout_w     = (const float*)d_in[21];
  const float* pout_b     = (const float*)d_in[22];
  const float* mlp_ln_g   = (const float*)d_in[23];
  const float* mlp_ln_b   = (const float*)d_in[24];
  const float* mlp_w1     = (const float*)d_in[25];
  const float* mlp_b1     = (const float*)d_in[26];
  const float* mlp_w2     = (const float*)d_in[27];
  const float* mlp_b2     = (const float*)d_in[28];

  char* ws = (char*)d_ws;
  short* lnq  = (short*)(ws + 0);            // 8.39 MB
  short* lnp  = (short*)(ws + 8388608);      // 8.39 MB
  short* qkvb = (short*)(ws + 16777216);     // 100.7 MB (dead after attn)
  short* avb  = (short*)(ws + 117440512);    // 33.6 MB
  float* projb= (float*)(ws + 16777216);     // alias qkv region
  float* ab   = (float*)(ws + 50331648);     // alias qkv region
  float* ub   = (float*)(ws + 83886080);     // alias qkv region
  short* vbfb = (short*)(ws + 117440512);    // alias av region
  short* outnb= (short*)(ws + 134217728);    // alias av region
  float* x1b  = (float*)(ws + 0);            // alias lnq/lnp region [0,16.8MB)
  short* lnxp = (short*)(ws + 150994944);    // 8.39 MB (tile-packed)
  short* h3p  = (short*)(ws + 159383552);    // 9.31 MB (tile-packed, 142 tiles)
  float* partb= (float*)(ws + 16777216);     // split-K partials (<=74.5 MB)

  ln_dual_k<<<8192, 256, 0, stream>>>(x, qkv_ln_g, qkv_ln_b, pin_ln_g, pin_ln_b, lnq, lnp);
  gemm_k<128,128,2,2,0><<<dim3(12,256), 256, 0, stream>>>(
      lnq, qkv_w, qkv_b, nullptr, qkvb, nullptr, 32768, 1536, 128, 1536, 128);
  attn_k<<<512, 256, 0, stream>>>(qkvb, rel_bias, scale, avb);
  gemm_k<128,128,2,2,1><<<dim3(2,256), 256, 0, stream>>>(
      avb, attn_pw, attn_pb, nullptr, projb, nullptr, 32768, 256, 512, 256, 512);
  ln256_k<<<8192, 256, 0, stream>>>(projb, attn_ln_g, attn_ln_b, ab);
  gemm_k<128,128,2,2,2><<<dim3(4,256), 256, 0, stream>>>(
      lnp, pin_w, pin_b, nullptr, ub, vbfb, 32768, 512, 128, 512, 128);
  gate_k<<<512, 256, 0, stream>>>(ub, vbfb, ab, sp_ln_g, sp_ln_b, sp_w, sp_b,
                                  pout_ln_g, pout_ln_b, outnb);
  gemm_k<128,128,2,2,3><<<dim3(1,256), 256, 0, stream>>>(
      outnb, pout_w, pout_b, x, x1b, nullptr, 32768, 128, 256, 128, 256);
  ln8192_k<<<512, 256, 0, stream>>>(x1b, mlp_ln_g, mlp_ln_b, lnxp);

  // mlp1: [512,8192] @ [8192,9011] (N padded 9088 = 71*128), split-K 3.
  // 213 blocks; chunks 43/43/42 steps. A = tile-packed lnxp.
  gemm_splitk9<<<213, 512, 0, stream>>>(
      lnxp, mlp_w1, partb, /*N=*/9088, /*K=*/8192, /*Kreal=*/8192,
      /*ldb=*/9011, /*kchunk=*/2752, /*ntiles=*/71);
  reduce_mlp1_k<<<dim3(9, 512), 256, 0, stream>>>(partb, mlp_b1, h3p, 9088, 9011, 512, 3);

  // mlp2: [512,9088] @ [9011,8192], split-K 4 (256 blocks; 36/36/36/34 steps).
  // A = tile-packed h3p.
  gemm_splitk9<<<256, 512, 0, stream>>>(
      h3p, mlp_w2, partb, /*N=*/8192, /*K=*/9088, /*Kreal=*/9011,
      /*ldb=*/8192, /*kchunk=*/2304, /*ntiles=*/64);
  reduce_mlp2_k<<<dim3(8, 512), 256, 0, stream>>>(partb, mlp_b2, x1b, (float*)d_out, 8192, 512, 4);
}

// Round 11
// 764.987 us; speedup vs baseline: 1.1522x; 1.0055x over previous
//
#include <hip/hip_runtime.h>
#include <hip/hip_bf16.h>
#include <math.h>

typedef float f32x4 __attribute__((ext_vector_type(4)));
typedef float f32x2 __attribute__((ext_vector_type(2)));
typedef short s16x8 __attribute__((ext_vector_type(8)));
typedef short s16x4 __attribute__((ext_vector_type(4)));
typedef int   i32x4 __attribute__((ext_vector_type(4)));

__device__ __forceinline__ short f2bf(float f) {
  __hip_bfloat16 h = __float2bfloat16(f);
  return __builtin_bit_cast(short, h);
}
__device__ __forceinline__ float bf2f(short s) {
  __hip_bfloat16 h = __builtin_bit_cast(__hip_bfloat16, s);
  return __bfloat162float(h);
}
__device__ __forceinline__ float gelu_f(float x) {
  return 0.5f * x * (1.f + erff(x * 0.70710678118654752440f));
}
__device__ __forceinline__ float waveSum(float v) {
  #pragma unroll
  for (int d = 32; d; d >>= 1) v += __shfl_xor(v, d);
  return v;
}
// Soft barrier: LDS-visibility only; does NOT drain vmcnt.
__device__ __forceinline__ void softBarrier() {
  asm volatile("s_waitcnt lgkmcnt(0)" ::: "memory");
  __builtin_amdgcn_s_barrier();
  asm volatile("" ::: "memory");
}

// ---------------------------------------------------------------------------
// F1: fused per-board attention branch.
// One block per board b: x[64][128] -> LN(qkv_ln) -> q,k,v = lnq @ qkv_w + b
// (weights staged transposed bf16 from L2, 128-col chunks) -> scores =
// q@k^T + rel_bias -> softmax*scale -> av = P@V (per 128-col chunk) ->
// proj += av_chunk @ attn_pw_chunk (register acc) -> +pb -> ln256 -> ab f32.
// Also emits lnp (pin_ln path) to global.
// All MFMA index conventions copied from the passing attn_k/gemm_k:
//   A-frag = A[ln15-row][hi*8 k], B-frag = B[ln15-col][hi*8 k],
//   C[j]: row = hi*4+j, col = ln15.
// ---------------------------------------------------------------------------
__global__ __launch_bounds__(256) void fused_attn_k(
    const float* __restrict__ x,
    const float* __restrict__ qln_g, const float* __restrict__ qln_b,
    const float* __restrict__ pln_g, const float* __restrict__ pln_b,
    const float* __restrict__ qkv_w, const float* __restrict__ qkv_b,
    const float* __restrict__ attn_pw, const float* __restrict__ attn_pb,
    const float* __restrict__ aln_g, const float* __restrict__ aln_b,
    const float* __restrict__ relb, const float* __restrict__ scale_p,
    short* __restrict__ lnp, float* __restrict__ ab)
{
  __shared__ __align__(16) char arena[159232];
  short (*lnq)[136]  = reinterpret_cast<short(*)[136]>(arena + 0);       // 17408
  short (*plds)[72]  = reinterpret_cast<short(*)[72]>(arena + 17408);    // 9216
  short (*vlds)[72]  = reinterpret_cast<short(*)[72]>(arena + 26624);    // 18432
  short (*avl)[136]  = reinterpret_cast<short(*)[136]>(arena + 26624);   // alias vlds
  short (*qlds)[136] = reinterpret_cast<short(*)[136]>(arena + 45056);   // 17408
  short (*klds)[136] = reinterpret_cast<short(*)[136]>(arena + 62464);   // 17408
  short (*pwT)[136]  = reinterpret_cast<short(*)[136]>(arena + 45056);   // 69632, alias q+k (phase D)
  short (*wT)[136]   = reinterpret_cast<short(*)[136]>(arena + 114688);  // 34816
  float* rb    = reinterpret_cast<float*>(arena + 149504);  // 127 f32
  float* s_apb = reinterpret_cast<float*>(arena + 150016);  // 256
  float* s_ag  = reinterpret_cast<float*>(arena + 151040);  // 256
  float* s_ab2 = reinterpret_cast<float*>(arena + 152064);  // 256
  float* sqb   = reinterpret_cast<float*>(arena + 153088);  // 1536

  const int t = threadIdx.x, lane = t & 63, w = t >> 6;
  const int ln15 = lane & 15, hi = lane >> 4;
  const int b = blockIdx.x;

  // stage small constants
  if (t < 127) rb[t] = relb[t];
  s_apb[t] = attn_pb[t]; s_ag[t] = aln_g[t]; s_ab2[t] = aln_b[t];
  #pragma unroll
  for (int i = 0; i < 6; ++i) sqb[i*256 + t] = qkv_b[i*256 + t];

  // Phase A: row LN -> lnq (LDS bf16) and lnp (global bf16)
  {
    int c = lane * 2;
    float qg0 = qln_g[c], qg1 = qln_g[c+1], qb0 = qln_b[c], qb1 = qln_b[c+1];
    float pg0 = pln_g[c], pg1 = pln_g[c+1], pb0 = pln_b[c], pb1 = pln_b[c+1];
    for (int i = 0; i < 16; ++i) {
      int r = w * 16 + i;
      f32x2 v = *reinterpret_cast<const f32x2*>(&x[((size_t)b*64 + r)*128 + c]);
      float s = v[0] + v[1], sq = v[0]*v[0] + v[1]*v[1];
      s = waveSum(s); sq = waveSum(sq);
      float m = s * (1.f/128.f);
      float rstd = rsqrtf(sq*(1.f/128.f) - m*m + 1e-5f);
      float a0 = (v[0]-m)*rstd, a1 = (v[1]-m)*rstd;
      unsigned q0 = (unsigned short)f2bf(a0*qg0 + qb0);
      unsigned q1 = (unsigned short)f2bf(a1*qg1 + qb1);
      *reinterpret_cast<unsigned*>(&lnq[r][c]) = q0 | (q1 << 16);
      unsigned p0 = (unsigned short)f2bf(a0*pg0 + pb0);
      unsigned p1 = (unsigned short)f2bf(a1*pg1 + pb1);
      ((unsigned*)lnp)[((size_t)b*64 + r)*64 + lane] = p0 | (p1 << 16);
    }
  }
  __syncthreads();

  // stage a 128-col chunk of qkv_w (128 x 1536) transposed bf16 into wT
  auto stageW = [&](int coff) {
    #pragma unroll
    for (int i = 0; i < 16; ++i) {
      int e = i*256 + t;
      int k = e >> 5, c4 = (e & 31) * 4;
      f32x4 v = *reinterpret_cast<const f32x4*>(&qkv_w[(size_t)k*1536 + coff + c4]);
      wT[c4+0][k] = f2bf(v[0]); wT[c4+1][k] = f2bf(v[1]);
      wT[c4+2][k] = f2bf(v[2]); wT[c4+3][k] = f2bf(v[3]);
    }
  };
  // out (64 x 128chunk) = lnq (64x128) @ wT  — 8 col-frags per wave
  auto gemm8 = [&](f32x4 (&acc)[8]) {
    #pragma unroll
    for (int kk = 0; kk < 4; ++kk) {
      s16x8 af = *reinterpret_cast<const s16x8*>(&lnq[w*16 + ln15][kk*32 + hi*8]);
      #pragma unroll
      for (int fn = 0; fn < 8; ++fn) {
        s16x8 bf = *reinterpret_cast<const s16x8*>(&wT[fn*16 + ln15][kk*32 + hi*8]);
        acc[fn] = __builtin_amdgcn_mfma_f32_16x16x32_bf16(af, bf, acc[fn], 0, 0, 0);
      }
    }
  };

  // Phase B: scores = q @ k^T accumulated over 4 x 128-d chunks
  f32x4 sacc[4] = {};
  for (int kc = 0; kc < 4; ++kc) {
    __syncthreads();                       // prior qlds/klds readers done
    stageW(kc * 128);                      // wq chunk
    __syncthreads();
    {
      f32x4 qa[8] = {};
      gemm8(qa);
      #pragma unroll
      for (int fn = 0; fn < 8; ++fn) {
        float bias = sqb[kc*128 + fn*16 + ln15];
        #pragma unroll
        for (int j = 0; j < 4; ++j)
          qlds[w*16 + hi*4 + j][fn*16 + ln15] = f2bf(qa[fn][j] + bias);
      }
    }
    __syncthreads();                       // qlds visible; wT reads done
    stageW(512 + kc * 128);                // wk chunk
    __syncthreads();
    {
      f32x4 ka[8] = {};
      gemm8(ka);
      #pragma unroll
      for (int fn = 0; fn < 8; ++fn) {
        float bias = sqb[512 + kc*128 + fn*16 + ln15];
        #pragma unroll
        for (int j = 0; j < 4; ++j)
          klds[w*16 + hi*4 + j][fn*16 + ln15] = f2bf(ka[fn][j] + bias);
      }
    }
    __syncthreads();                       // klds visible
    #pragma unroll
    for (int kk = 0; kk < 4; ++kk) {
      s16x8 aq = *reinterpret_cast<const s16x8*>(&qlds[16*w + ln15][kk*32 + hi*8]);
      #pragma unroll
      for (int fn = 0; fn < 4; ++fn) {
        s16x8 bk = *reinterpret_cast<const s16x8*>(&klds[fn*16 + ln15][kk*32 + hi*8]);
        sacc[fn] = __builtin_amdgcn_mfma_f32_16x16x32_bf16(aq, bk, sacc[fn], 0, 0, 0);
      }
    }
  }

  // softmax + post-softmax scale -> plds bf16
  {
    float scale = scale_p[0];
    #pragma unroll
    for (int j = 0; j < 4; ++j) {
      int row = 16*w + hi*4 + j;
      float pv[4];
      float mx = -1e30f;
      #pragma unroll
      for (int fn = 0; fn < 4; ++fn) {
        int col = fn*16 + ln15;
        pv[fn] = sacc[fn][j] + rb[col - row + 63];
        mx = fmaxf(mx, pv[fn]);
      }
      #pragma unroll
      for (int d = 1; d < 16; d <<= 1) mx = fmaxf(mx, __shfl_xor(mx, d));
      float sum = 0.f;
      #pragma unroll
      for (int fn = 0; fn < 4; ++fn) { pv[fn] = __expf(pv[fn] - mx); sum += pv[fn]; }
      #pragma unroll
      for (int d = 1; d < 16; d <<= 1) sum += __shfl_xor(sum, d);
      float inv = scale / sum;
      #pragma unroll
      for (int fn = 0; fn < 4; ++fn) plds[row][fn*16 + ln15] = f2bf(pv[fn] * inv);
    }
  }
  __syncthreads();

  // Phase D: per 128-col chunk: v -> vlds^T -> av = P@V -> proj += av @ pw
  f32x4 pracc[16] = {};
  for (int cc = 0; cc < 4; ++cc) {
    __syncthreads();                       // prior pwT/avl readers done
    stageW(1024 + cc * 128);               // wv chunk -> wT
    #pragma unroll
    for (int i = 0; i < 32; ++i) {         // attn_pw rows cc*128..+128 -> pwT
      int e = i*256 + t;
      int k = e >> 6, c4 = (e & 63) * 4;
      f32x4 v = *reinterpret_cast<const f32x4*>(&attn_pw[(size_t)(cc*128 + k)*256 + c4]);
      pwT[c4+0][k] = f2bf(v[0]); pwT[c4+1][k] = f2bf(v[1]);
      pwT[c4+2][k] = f2bf(v[2]); pwT[c4+3][k] = f2bf(v[3]);
    }
    __syncthreads();
    {
      f32x4 va[8] = {};
      gemm8(va);
      #pragma unroll
      for (int fn = 0; fn < 8; ++fn) {
        float bias = sqb[1024 + cc*128 + fn*16 + ln15];
        #pragma unroll
        for (int j = 0; j < 4; ++j)
          vlds[fn*16 + ln15][w*16 + hi*4 + j] = f2bf(va[fn][j] + bias);  // transposed
      }
    }
    __syncthreads();                       // vlds visible
    f32x4 pacc[8] = {};
    #pragma unroll
    for (int kk = 0; kk < 2; ++kk) {
      s16x8 ap = *reinterpret_cast<const s16x8*>(&plds[16*w + ln15][kk*32 + hi*8]);
      #pragma unroll
      for (int fn = 0; fn < 8; ++fn) {
        s16x8 bv = *reinterpret_cast<const s16x8*>(&vlds[fn*16 + ln15][kk*32 + hi*8]);
        pacc[fn] = __builtin_amdgcn_mfma_f32_16x16x32_bf16(ap, bv, pacc[fn], 0, 0, 0);
      }
    }
    __syncthreads();                       // vlds reads done -> reuse as avl
    #pragma unroll
    for (int fn = 0; fn < 8; ++fn)
      #pragma unroll
      for (int j = 0; j < 4; ++j)
        avl[w*16 + hi*4 + j][fn*16 + ln15] = f2bf(pacc[fn][j]);
    __syncthreads();                       // avl visible
    #pragma unroll
    for (int kk = 0; kk < 4; ++kk) {
      s16x8 aa = *reinterpret_cast<const s16x8*>(&avl[16*w + ln15][kk*32 + hi*8]);
      #pragma unroll
      for (int fn = 0; fn < 16; ++fn) {
        s16x8 pb = *reinterpret_cast<const s16x8*>(&pwT[fn*16 + ln15][kk*32 + hi*8]);
        pracc[fn] = __builtin_amdgcn_mfma_f32_16x16x32_bf16(aa, pb, pracc[fn], 0, 0, 0);
      }
    }
  }

  // proj epilogue: +pb, LN over 256 (cross-lane within 16-lane group), -> ab f32
  #pragma unroll
  for (int j = 0; j < 4; ++j) {
    int row = 16*w + hi*4 + j;
    float vv[16];
    float s = 0.f, sq = 0.f;
    #pragma unroll
    for (int fn = 0; fn < 16; ++fn) {
      vv[fn] = pracc[fn][j] + s_apb[fn*16 + ln15];
      s += vv[fn]; sq += vv[fn]*vv[fn];
    }
    #pragma unroll
    for (int d = 1; d < 16; d <<= 1) { s += __shfl_xor(s, d); sq += __shfl_xor(sq, d); }
    float m = s * (1.f/256.f);
    float rstd = rsqrtf(sq*(1.f/256.f) - m*m + 1e-5f);
    #pragma unroll
    for (int fn = 0; fn < 16; ++fn) {
      int col = fn*16 + ln15;
      ab[((size_t)b*64 + row)*256 + col] = (vv[fn]-m)*rstd*s_ag[col] + s_ab2[col];
    }
  }
}

// ---------------------------------------------------------------------------
// Generic bf16-MFMA GEMM for the small GEMMs.
// EPI: 2 = gelu split u/v (pin); 3 = f32 out (+bias +res)
// ---------------------------------------------------------------------------
template<int BM, int BN, int WM, int WN, int EPI>
__global__ __launch_bounds__(256) void gemm_k(
    const short* __restrict__ A, const float* __restrict__ Bw,
    const float* __restrict__ bias, const float* __restrict__ res,
    void* __restrict__ O0, void* __restrict__ O1,
    int M, int N, int K, int Nreal, int Kreal)
{
  constexpr int BK = 64;
  __shared__ __align__(16) short As[BM][BK + 8];
  __shared__ __align__(16) short Bs[BN][BK + 8];
  const int t = threadIdx.x;
  const int lane = t & 63;
  const int w = t >> 6;
  const int wm = w / WN, wn = w % WN;
  const int ln15 = lane & 15, hi = lane >> 4;
  const int m0 = blockIdx.y * BM;
  const int n0 = blockIdx.x * BN;

  f32x4 acc[4][4] = {};

  for (int k0 = 0; k0 < K; k0 += BK) {
    #pragma unroll
    for (int i = 0; i < (BM*BK)/(256*8); ++i) {
      int e = (i*256 + t) * 8;
      int r = e / BK, c = e % BK;
      *reinterpret_cast<i32x4*>(&As[r][c]) =
          *reinterpret_cast<const i32x4*>(&A[(size_t)(m0 + r) * K + k0 + c]);
    }
    #pragma unroll
    for (int i = 0; i < (BK*BN)/256; ++i) {
      int idx = i*256 + t;
      int n = idx % BN, k = idx / BN;
      int gk = k0 + k, gn = n0 + n;
      float v = (gk < Kreal && gn < Nreal) ? Bw[(size_t)gk * Nreal + gn] : 0.f;
      Bs[n][k] = f2bf(v);
    }
    __syncthreads();
    #pragma unroll
    for (int kk = 0; kk < BK; kk += 32) {
      s16x8 af[4], bfr[4];
      #pragma unroll
      for (int fm = 0; fm < 4; ++fm)
        af[fm] = *reinterpret_cast<const s16x8*>(&As[wm*64 + fm*16 + ln15][kk + hi*8]);
      #pragma unroll
      for (int fn = 0; fn < 4; ++fn)
        bfr[fn] = *reinterpret_cast<const s16x8*>(&Bs[wn*64 + fn*16 + ln15][kk + hi*8]);
      #pragma unroll
      for (int fm = 0; fm < 4; ++fm)
        #pragma unroll
        for (int fn = 0; fn < 4; ++fn)
          acc[fm][fn] = __builtin_amdgcn_mfma_f32_16x16x32_bf16(
              af[fm], bfr[fn], acc[fm][fn], 0, 0, 0);
    }
    __syncthreads();
  }

  #pragma unroll
  for (int fm = 0; fm < 4; ++fm) {
    #pragma unroll
    for (int fn = 0; fn < 4; ++fn) {
      #pragma unroll
      for (int j = 0; j < 4; ++j) {
        int row = m0 + wm*64 + fm*16 + hi*4 + j;
        int col = n0 + wn*64 + fn*16 + ln15;
        float v = acc[fm][fn][j];
        if constexpr (EPI == 2) {
          v = gelu_f(v + bias[col]);
          if (col < 256) ((float*)O0)[(size_t)row * 256 + col] = v;
          else ((short*)O1)[(size_t)row * 256 + (col - 256)] = f2bf(v);
        } else { // 3
          v += bias[col] + res[(size_t)row * N + col];
          ((float*)O0)[(size_t)row * N + col] = v;
        }
      }
    }
  }
}

// ---------------------------------------------------------------------------
// K3: LayerNorm over 8192 (mlp_ln) -> bf16, TILE-PACKED output
// ---------------------------------------------------------------------------
__global__ __launch_bounds__(256) void ln8192_k(
    const float* __restrict__ x1,
    const float* __restrict__ g, const float* __restrict__ bb,
    short* __restrict__ lnxp)
{
  __shared__ float red[8];
  int t = threadIdx.x, w = t >> 6, lane = t & 63;
  int b = blockIdx.x;
  const f32x4* xr = reinterpret_cast<const f32x4*>(x1 + (size_t)b * 8192);
  f32x4 vals[8];
  float s = 0.f, sq = 0.f;
  #pragma unroll
  for (int i = 0; i < 8; ++i) {
    f32x4 v = xr[t + i*256];
    vals[i] = v;
    s  += v[0]+v[1]+v[2]+v[3];
    sq += v[0]*v[0]+v[1]*v[1]+v[2]*v[2]+v[3]*v[3];
  }
  s = waveSum(s); sq = waveSum(sq);
  if (lane == 0) { red[w] = s; red[4+w] = sq; }
  __syncthreads();
  s  = red[0]+red[1]+red[2]+red[3];
  sq = red[4]+red[5]+red[6]+red[7];
  float m = s * (1.f/8192.f);
  float rstd = rsqrtf(sq * (1.f/8192.f) - m*m + 1e-5f);
  #pragma unroll
  for (int i = 0; i < 8; ++i) {
    int idx = (t + i*256) * 4;
    f32x4 g4 = reinterpret_cast<const f32x4*>(g)[t + i*256];
    f32x4 b4 = reinterpret_cast<const f32x4*>(bb)[t + i*256];
    s16x4 o;
    #pragma unroll
    for (int k = 0; k < 4; ++k) o[k] = f2bf((vals[i][k]-m)*rstd*g4[k] + b4[k]);
    size_t paddr = ((size_t)(idx >> 6) * 512 + b) * 64 + (idx & 63);
    *reinterpret_cast<s16x4*>(&lnxp[paddr]) = o;
  }
}

// ---------------------------------------------------------------------------
// Split-K GEMM v9 (unchanged from R10): tile-packed A, B dbuf LDS w/ XOR
// swizzle, write-early/load-late, soft barriers.
// ---------------------------------------------------------------------------
__global__ __launch_bounds__(512, 2) void gemm_splitk9(
    const short* __restrict__ Ap, const float* __restrict__ Bw,
    float* __restrict__ part,
    int N, int K, int Kreal, int ldb, int kchunk, int ntiles)
{
  __shared__ __align__(16) short Bs[2][128 * 64];
  const int t = threadIdx.x, lane = t & 63, w = t >> 6;
  const int ln15 = lane & 15, hi = lane >> 4;
  const int nt = blockIdx.x % ntiles, z = blockIdx.x / ntiles;
  const int n0 = nt * 128;
  const int kbeg = z * kchunk;
  const int kend = (kbeg + kchunk < K) ? (kbeg + kchunk) : K;
  const int nsteps = (kend - kbeg) >> 6;

  const int bn = t & 127;
  const int bg0 = (t >> 7) * 2;
  const bool bok = (n0 + bn) < ldb;
  const int bsw = bn & 7;

  float br[16];
  auto loadB = [&](int k0) {
    const float* bp = Bw + (size_t)(k0 + bg0 * 8) * ldb + n0 + bn;
    #pragma unroll
    for (int m = 0; m < 16; ++m) {
      int gk = k0 + bg0 * 8 + m;
      br[m] = (bok && gk < Kreal) ? bp[(size_t)m * ldb] : 0.f;
    }
  };
  auto writeB = [&](int buf) {
    s16x8 v0, v1;
    #pragma unroll
    for (int m = 0; m < 8; ++m) { v0[m] = f2bf(br[m]); v1[m] = f2bf(br[8 + m]); }
    short* dst = &Bs[buf][bn * 64];
    *reinterpret_cast<s16x8*>(dst + ((bg0    ) ^ bsw) * 8) = v0;
    *reinterpret_cast<s16x8*>(dst + ((bg0 + 1) ^ bsw) * 8) = v1;
  };

  f32x4 acc[4][8] = {};

  loadB(kbeg);
  writeB(0);
  if (nsteps > 1) loadB(kbeg + 64);
  softBarrier();

  for (int s = 0; s < nsteps; ++s) {
    const int k0 = kbeg + s * 64;
    const short* atile = Ap + (size_t)(k0 >> 6) * 512 * 64;
    s16x8 af[8];
    #pragma unroll
    for (int kk = 0; kk < 2; ++kk)
      #pragma unroll
      for (int fm = 0; fm < 4; ++fm) {
        int row = w * 64 + fm * 16 + ln15;
        af[kk * 4 + fm] = *reinterpret_cast<const s16x8*>(
            &atile[row * 64 + (kk * 4 + hi) * 8]);
      }
    if (s + 1 < nsteps) writeB((s + 1) & 1);
    if (s + 2 < nsteps) loadB(kbeg + (s + 2) * 64);

    const short* bsrc = &Bs[s & 1][0];
    #pragma unroll
    for (int kk = 0; kk < 2; ++kk) {
      const int g = kk * 4 + hi;
      #pragma unroll
      for (int fn = 0; fn < 8; ++fn) {
        int row = fn * 16 + ln15;
        s16x8 bv = *reinterpret_cast<const s16x8*>(
            &bsrc[row * 64 + ((g ^ (row & 7)) * 8)]);
        #pragma unroll
        for (int fm = 0; fm < 4; ++fm)
          acc[fm][fn] = __builtin_amdgcn_mfma_f32_16x16x32_bf16(
              af[kk * 4 + fm], bv, acc[fm][fn], 0, 0, 0);
      }
    }
    softBarrier();
  }

  #pragma unroll
  for (int fm = 0; fm < 4; ++fm)
    #pragma unroll
    for (int fn = 0; fn < 8; ++fn)
      #pragma unroll
      for (int j = 0; j < 4; ++j) {
        int row = w * 64 + fm * 16 + hi * 4 + j;
        int col = n0 + fn * 16 + ln15;
        part[((size_t)z * 512 + row) * N + col] = acc[fm][fn][j];
      }
}

// ---------------------------------------------------------------------------
// split-K reduce for mlp1: h3 = gelu(sum part + b1), bf16, TILE-PACKED out
// ---------------------------------------------------------------------------
__global__ __launch_bounds__(256) void reduce_mlp1_k(
    const float* __restrict__ part, const float* __restrict__ bias,
    short* __restrict__ h3p, int N, int Nreal, int M, int ks)
{
  int col4 = (blockIdx.x * 256 + threadIdx.x) * 4;
  int row = blockIdx.y;
  if (col4 >= N) return;
  size_t base = (size_t)row * N + col4;
  size_t stride = (size_t)M * N;
  f32x4 s = *reinterpret_cast<const f32x4*>(part + base);
  for (int k = 1; k < ks; ++k)
    s += *reinterpret_cast<const f32x4*>(part + base + (size_t)k * stride);
  s16x4 o;
  #pragma unroll
  for (int j = 0; j < 4; ++j) {
    int c = col4 + j;
    float v = 0.f;
    if (c < Nreal) v = gelu_f(s[j] + bias[c]);
    o[j] = f2bf(v);
  }
  size_t paddr = ((size_t)(col4 >> 6) * 512 + row) * 64 + (col4 & 63);
  *reinterpret_cast<s16x4*>(&h3p[paddr]) = o;
}

// ---------------------------------------------------------------------------
// split-K reduce for mlp2: out = sum part + b2 + x1 (f32)
// ---------------------------------------------------------------------------
__global__ __launch_bounds__(256) void reduce_mlp2_k(
    const float* __restrict__ part, const float* __restrict__ bias,
    const float* __restrict__ x1, float* __restrict__ out, int N, int M, int ks)
{
  int col4 = (blockIdx.x * 256 + threadIdx.x) * 4;
  int row = blockIdx.y;
  size_t base = (size_t)row * N + col4;
  size_t stride = (size_t)M * N;
  f32x4 s = *reinterpret_cast<const f32x4*>(part + base);
  for (int k = 1; k < ks; ++k)
    s += *reinterpret_cast<const f32x4*>(part + base + (size_t)k * stride);
  f32x4 b4 = *reinterpret_cast<const f32x4*>(bias + col4);
  f32x4 r4 = *reinterpret_cast<const f32x4*>(x1 + base);
  #pragma unroll
  for (int j = 0; j < 4; ++j) s[j] += b4[j] + r4[j];
  *reinterpret_cast<f32x4*>(out + base) = s;
}

// ---------------------------------------------------------------------------
// K5: SGU gate (unchanged)
// ---------------------------------------------------------------------------
__global__ __launch_bounds__(256) void gate_k(
    const float* __restrict__ u, const short* __restrict__ vbf,
    const float* __restrict__ a,
    const float* __restrict__ spg_g, const float* __restrict__ spg_b,
    const float* __restrict__ spw, const float* __restrict__ spb,
    const float* __restrict__ pog, const float* __restrict__ pob,
    short* __restrict__ outn)
{
  __shared__ __align__(16) short nvb[256][72];
  __shared__ __align__(16) short spwT[64][72];
  __shared__ float s_spg[64], s_spbl[64], s_spb[64];
  __shared__ float s_pog[256], s_pob[256];
  int t = threadIdx.x, lane = t & 63, w = t >> 6;
  int ln15 = lane & 15, hi = lane >> 4;
  int b = blockIdx.x;

  if (t < 64) { s_spg[t] = spg_g[t]; s_spbl[t] = spg_b[t]; s_spb[t] = spb[t]; }
  s_pog[t] = pog[t]; s_pob[t] = pob[t];
  #pragma unroll
  for (int i = 0; i < 16; ++i) {
    int idx = i*256 + t;
    int sr = idx >> 6, tc = idx & 63;
    spwT[tc][sr] = f2bf(spw[idx]);
  }

  float vvv[64];
  {
    int c = t;
    float s = 0.f, sq = 0.f;
    #pragma unroll
    for (int si = 0; si < 64; ++si) {
      float f = bf2f(vbf[(size_t)(b*64 + si) * 256 + c]);
      vvv[si] = f; s += f; sq += f*f;
    }
    float m = s * (1.f/64.f);
    float rstd = rsqrtf(sq * (1.f/64.f) - m*m + 1e-5f);
    __syncthreads();
    #pragma unroll
    for (int si = 0; si < 64; ++si)
      nvb[c][si] = f2bf((vvv[si]-m)*rstd*s_spg[si] + s_spbl[si]);
  }
  __syncthreads();

  f32x4 yacc[4][4] = {};
  #pragma unroll
  for (int kk = 0; kk < 64; kk += 32) {
    s16x8 af[4], bfr[4];
    #pragma unroll
    for (int fm = 0; fm < 4; ++fm)
      af[fm] = *reinterpret_cast<const s16x8*>(&nvb[64*w + fm*16 + ln15][kk + hi*8]);
    #pragma unroll
    for (int fn = 0; fn < 4; ++fn)
      bfr[fn] = *reinterpret_cast<const s16x8*>(&spwT[fn*16 + ln15][kk + hi*8]);
    #pragma unroll
    for (int fm = 0; fm < 4; ++fm)
      #pragma unroll
      for (int fn = 0; fn < 4; ++fn)
        yacc[fm][fn] = __builtin_amdgcn_mfma_f32_16x16x32_bf16(
            af[fm], bfr[fn], yacc[fm][fn], 0, 0, 0);
  }
  __syncthreads();

  short (*outl)[264] = reinterpret_cast<short(*)[264]>(&nvb[0][0]);
  #pragma unroll
  for (int fm = 0; fm < 4; ++fm) {
    #pragma unroll
    for (int fn = 0; fn < 4; ++fn) {
      int crow = 64*w + fm*16 + hi*4;
      int tcol = fn*16 + ln15;
      f32x4 u4 = *reinterpret_cast<const f32x4*>(&u[(size_t)(b*64 + tcol)*256 + crow]);
      f32x4 a4 = *reinterpret_cast<const f32x4*>(&a[(size_t)(b*64 + tcol)*256 + crow]);
      #pragma unroll
      for (int j = 0; j < 4; ++j) {
        float g = gelu_f(yacc[fm][fn][j] + s_spb[tcol]);
        float o = u4[j] * (g + a4[j]);
        outl[tcol][crow + j] = f2bf(o);
      }
    }
  }
  __syncthreads();

  #pragma unroll
  for (int ri = 0; ri < 16; ++ri) {
    int trow = w*16 + ri;
    int c = lane * 4;
    s16x4 raw = *reinterpret_cast<const s16x4*>(&outl[trow][c]);
    float f0 = bf2f(raw[0]), f1 = bf2f(raw[1]), f2 = bf2f(raw[2]), f3 = bf2f(raw[3]);
    float s  = f0+f1+f2+f3;
    float sq = f0*f0+f1*f1+f2*f2+f3*f3;
    s = waveSum(s); sq = waveSum(sq);
    float m = s * (1.f/256.f);
    float rstd = rsqrtf(sq * (1.f/256.f) - m*m + 1e-5f);
    s16x4 o;
    o[0] = f2bf((f0-m)*rstd*s_pog[c+0] + s_pob[c+0]);
    o[1] = f2bf((f1-m)*rstd*s_pog[c+1] + s_pob[c+1]);
    o[2] = f2bf((f2-m)*rstd*s_pog[c+2] + s_pob[c+2]);
    o[3] = f2bf((f3-m)*rstd*s_pog[c+3] + s_pob[c+3]);
    *reinterpret_cast<s16x4*>(&outn[(size_t)(b*64 + trow)*256 + c]) = o;
  }
}

// ---------------------------------------------------------------------------
extern "C" void kernel_launch(void* const* d_in, const int* in_sizes, int n_in,
                              void* d_out, int out_size, void* d_ws, size_t ws_size,
                              hipStream_t stream)
{
  const float* x          = (const float*)d_in[0];
  const float* qkv_ln_g   = (const float*)d_in[1];
  const float* qkv_ln_b   = (const float*)d_in[2];
  const float* qkv_w      = (const float*)d_in[3];
  const float* qkv_b      = (const float*)d_in[4];
  const float* attn_pw    = (const float*)d_in[5];
  const float* attn_pb    = (const float*)d_in[6];
  const float* attn_ln_g  = (const float*)d_in[7];
  const float* attn_ln_b  = (const float*)d_in[8];
  const float* rel_bias   = (const float*)d_in[9];
  const float* scale      = (const float*)d_in[10];
  const float* pin_ln_g   = (const float*)d_in[11];
  const float* pin_ln_b   = (const float*)d_in[12];
  const float* pin_w      = (const float*)d_in[13];
  const float* pin_b      = (const float*)d_in[14];
  const float* sp_ln_g    = (const float*)d_in[15];
  const float* sp_ln_b    = (const float*)d_in[16];
  const float* sp_w       = (const float*)d_in[17];
  const float* sp_b       = (const float*)d_in[18];
  const float* pout_ln_g  = (const float*)d_in[19];
  const float* pout_ln_b  = (const float*)d_in[20];
  const float* pout_w     = (const float*)d_in[21];
  const float* pout_b     = (const float*)d_in[22];
  const float* mlp_ln_g   = (const float*)d_in[23];
  const float* mlp_ln_b   = (const float*)d_in[24];
  const float* mlp_w1     = (const float*)d_in[25];
  const float* mlp_b1     = (const float*)d_in[26];
  const float* mlp_w2     = (const float*)d_in[27];
  const float* mlp_b2     = (const float*)d_in[28];

  char* ws = (char*)d_ws;
  short* lnp   = (short*)(ws + 0);           // 8.39 MB (dead after pin gemm)
  float* x1b   = (float*)(ws + 0);           // 16.78 MB (written at pout)
  float* ab    = (float*)(ws + 16777216);    // 33.55 MB f32
  float* ub    = (float*)(ws + 50331648);    // 33.55 MB f32
  short* vbfb  = (short*)(ws + 83886080);    // 16.78 MB bf16
  short* outnb = (short*)(ws + 100663296);   // 16.78 MB bf16
  short* lnxp  = (short*)(ws + 150994944);   // 8.39 MB (tile-packed)
  short* h3p   = (short*)(ws + 159383552);   // 9.31 MB (tile-packed)
  float* partb = (float*)(ws + 16777216);    // split-K partials (aliases
                                             // ab/ub/vbf/outn region, <=67 MB)

  // fused: LN + qkv + attention + proj + ln256  ->  lnp, ab
  fused_attn_k<<<512, 256, 0, stream>>>(
      x, qkv_ln_g, qkv_ln_b, pin_ln_g, pin_ln_b, qkv_w, qkv_b,
      attn_pw, attn_pb, attn_ln_g, attn_ln_b, rel_bias, scale, lnp, ab);
  // pin: [32768,128]@[128,512]+b, gelu, split u (f32) / v (bf16)
  gemm_k<128,128,2,2,2><<<dim3(4,256), 256, 0, stream>>>(
      lnp, pin_w, pin_b, nullptr, ub, vbfb, 32768, 512, 128, 512, 128);
  // SGU gate + fused pout_ln -> outn bf16
  gate_k<<<512, 256, 0, stream>>>(ub, vbfb, ab, sp_ln_g, sp_ln_b, sp_w, sp_b,
                                  pout_ln_g, pout_ln_b, outnb);
  // pout: [32768,256]@[256,128]+b + x residual -> x1 f32
  gemm_k<128,128,2,2,3><<<dim3(1,256), 256, 0, stream>>>(
      outnb, pout_w, pout_b, x, x1b, nullptr, 32768, 128, 256, 128, 256);
  // LN over 8192 -> lnx (tile-packed)
  ln8192_k<<<512, 256, 0, stream>>>(x1b, mlp_ln_g, mlp_ln_b, lnxp);

  // mlp1: [512,8192] @ [8192,9011] (N padded 9088), split-K 3, 213 blocks
  gemm_splitk9<<<213, 512, 0, stream>>>(
      lnxp, mlp_w1, partb, /*N=*/9088, /*K=*/8192, /*Kreal=*/8192,
      /*ldb=*/9011, /*kchunk=*/2752, /*ntiles=*/71);
  reduce_mlp1_k<<<dim3(9, 512), 256, 0, stream>>>(partb, mlp_b1, h3p, 9088, 9011, 512, 3);

  // mlp2: [512,9088] @ [9011,8192], split-K 4, 256 blocks
  gemm_splitk9<<<256, 512, 0, stream>>>(
      h3p, mlp_w2, partb, /*N=*/8192, /*K=*/9088, /*Kreal=*/9011,
      /*ldb=*/8192, /*kchunk=*/2304, /*ntiles=*/64);
  reduce_mlp2_k<<<dim3(8, 512), 256, 0, stream>>>(partb, mlp_b2, x1b, (float*)d_out, 8192, 512, 4);
}

// Round 12
// 718.598 us; speedup vs baseline: 1.2265x; 1.0646x over previous
//
#include <hip/hip_runtime.h>
#include <hip/hip_bf16.h>
#include <math.h>

typedef float f32x4 __attribute__((ext_vector_type(4)));
typedef float f32x2 __attribute__((ext_vector_type(2)));
typedef short s16x8 __attribute__((ext_vector_type(8)));
typedef short s16x4 __attribute__((ext_vector_type(4)));
typedef int   i32x4 __attribute__((ext_vector_type(4)));

__device__ __forceinline__ short f2bf(float f) {
  __hip_bfloat16 h = __float2bfloat16(f);
  return __builtin_bit_cast(short, h);
}
__device__ __forceinline__ float bf2f(short s) {
  __hip_bfloat16 h = __builtin_bit_cast(__hip_bfloat16, s);
  return __bfloat162float(h);
}
__device__ __forceinline__ float gelu_f(float x) {
  return 0.5f * x * (1.f + erff(x * 0.70710678118654752440f));
}
__device__ __forceinline__ float waveSum(float v) {
  #pragma unroll
  for (int d = 32; d; d >>= 1) v += __shfl_xor(v, d);
  return v;
}
// Soft barrier: LDS-visibility only; does NOT drain vmcnt.
__device__ __forceinline__ void softBarrier() {
  asm volatile("s_waitcnt lgkmcnt(0)" ::: "memory");
  __builtin_amdgcn_s_barrier();
  asm volatile("" ::: "memory");
}

// ---------------------------------------------------------------------------
// F1: fused per-board attention branch (conflict-free staging rewrite).
// One block per board b: x[64][128] -> LN(qkv_ln) -> q,k,v = lnq @ qkv_w + b
// -> scores = q@k^T + rel_bias -> softmax*scale -> av = P@V -> proj ->
// +pb -> ln256 -> ab f32.  Also emits lnp.
// Weight transposes staged via OCTET-GATHER (one s16x8 row-write per thread,
// lane-coalesced strided loads) into [c][128] buffers with XOR octet swizzle
// o' = (o&8)|((o&7)^(c&7)) -- zero extra bank conflicts on write (floor) and
// 2-way (free) on MFMA B-frag reads.  (R11's scalar column writes were
// ~16-way: SQ_LDS_BANK_CONFLICT 8.6e7.)
// MFMA conventions identical to R11 (verified passing).
// ---------------------------------------------------------------------------
__global__ __launch_bounds__(256) void fused_attn_k(
    const float* __restrict__ x,
    const float* __restrict__ qln_g, const float* __restrict__ qln_b,
    const float* __restrict__ pln_g, const float* __restrict__ pln_b,
    const float* __restrict__ qkv_w, const float* __restrict__ qkv_b,
    const float* __restrict__ attn_pw, const float* __restrict__ attn_pb,
    const float* __restrict__ aln_g, const float* __restrict__ aln_b,
    const float* __restrict__ relb, const float* __restrict__ scale_p,
    short* __restrict__ lnp, float* __restrict__ ab)
{
  __shared__ __align__(16) char arena[153088];
  short (*lnq)[136]  = reinterpret_cast<short(*)[136]>(arena + 0);       // 17408
  short (*plds)[72]  = reinterpret_cast<short(*)[72]>(arena + 17408);    // 9216
  short (*vlds)[72]  = reinterpret_cast<short(*)[72]>(arena + 26624);    // 18432
  short (*avl)[136]  = reinterpret_cast<short(*)[136]>(arena + 26624);   // alias vlds
  short (*qlds)[136] = reinterpret_cast<short(*)[136]>(arena + 45056);   // 17408 (phase B)
  short (*klds)[136] = reinterpret_cast<short(*)[136]>(arena + 62464);   // 17408 (phase B)
  short (*pwT)[128]  = reinterpret_cast<short(*)[128]>(arena + 45056);   // 65536 (phase D, alias q+k+gap)
  short (*wT)[128]   = reinterpret_cast<short(*)[128]>(arena + 110592);  // 32768
  float* rb    = reinterpret_cast<float*>(arena + 143360);  // 127 f32
  float* s_apb = reinterpret_cast<float*>(arena + 143872);  // 256
  float* s_ag  = reinterpret_cast<float*>(arena + 144896);  // 256
  float* s_ab2 = reinterpret_cast<float*>(arena + 145920);  // 256
  float* sqb   = reinterpret_cast<float*>(arena + 146944);  // 1536

  const int t = threadIdx.x, lane = t & 63, w = t >> 6;
  const int ln15 = lane & 15, hi = lane >> 4;
  const int b = blockIdx.x;

  // stage small constants
  if (t < 127) rb[t] = relb[t];
  s_apb[t] = attn_pb[t]; s_ag[t] = aln_g[t]; s_ab2[t] = aln_b[t];
  #pragma unroll
  for (int i = 0; i < 6; ++i) sqb[i*256 + t] = qkv_b[i*256 + t];

  // Phase A: row LN -> lnq (LDS bf16) and lnp (global bf16)
  {
    int c = lane * 2;
    float qg0 = qln_g[c], qg1 = qln_g[c+1], qb0 = qln_b[c], qb1 = qln_b[c+1];
    float pg0 = pln_g[c], pg1 = pln_g[c+1], pb0 = pln_b[c], pb1 = pln_b[c+1];
    for (int i = 0; i < 16; ++i) {
      int r = w * 16 + i;
      f32x2 v = *reinterpret_cast<const f32x2*>(&x[((size_t)b*64 + r)*128 + c]);
      float s = v[0] + v[1], sq = v[0]*v[0] + v[1]*v[1];
      s = waveSum(s); sq = waveSum(sq);
      float m = s * (1.f/128.f);
      float rstd = rsqrtf(sq*(1.f/128.f) - m*m + 1e-5f);
      float a0 = (v[0]-m)*rstd, a1 = (v[1]-m)*rstd;
      unsigned q0 = (unsigned short)f2bf(a0*qg0 + qb0);
      unsigned q1 = (unsigned short)f2bf(a1*qg1 + qb1);
      *reinterpret_cast<unsigned*>(&lnq[r][c]) = q0 | (q1 << 16);
      unsigned p0 = (unsigned short)f2bf(a0*pg0 + pb0);
      unsigned p1 = (unsigned short)f2bf(a1*pg1 + pb1);
      ((unsigned*)lnp)[((size_t)b*64 + r)*64 + lane] = p0 | (p1 << 16);
    }
  }
  __syncthreads();

  // stage a 128-col chunk of qkv_w transposed (octet-gather, XOR swizzle)
  auto stageW = [&](int coff) {
    const int c = t & 127, h = t >> 7;
    #pragma unroll
    for (int j = 0; j < 8; ++j) {
      int o = h * 8 + j;
      s16x8 v;
      #pragma unroll
      for (int m = 0; m < 8; ++m)
        v[m] = f2bf(qkv_w[(size_t)(o*8 + m) * 1536 + coff + c]);
      int os = (o & 8) | ((o & 7) ^ (c & 7));
      *reinterpret_cast<s16x8*>(&wT[c][os * 8]) = v;
    }
  };
  // stage attn_pw chunk cc (128 rows x 256 cols) transposed into pwT
  auto stagePW = [&](int cc) {
    const int c = t;   // 0..255
    #pragma unroll
    for (int o = 0; o < 16; ++o) {
      s16x8 v;
      #pragma unroll
      for (int m = 0; m < 8; ++m)
        v[m] = f2bf(attn_pw[(size_t)(cc*128 + o*8 + m) * 256 + c]);
      int os = (o & 8) | ((o & 7) ^ (c & 7));
      *reinterpret_cast<s16x8*>(&pwT[c][os * 8]) = v;
    }
  };
  // out (64 x 128chunk) = lnq (64x128) @ wT  — 8 col-frags per wave
  auto gemm8 = [&](f32x4 (&acc)[8]) {
    #pragma unroll
    for (int kk = 0; kk < 4; ++kk) {
      s16x8 af = *reinterpret_cast<const s16x8*>(&lnq[w*16 + ln15][kk*32 + hi*8]);
      const int o = kk*4 + hi;
      #pragma unroll
      for (int fn = 0; fn < 8; ++fn) {
        int col = fn*16 + ln15;
        int os = (o & 8) | ((o & 7) ^ (col & 7));
        s16x8 bf = *reinterpret_cast<const s16x8*>(&wT[col][os * 8]);
        acc[fn] = __builtin_amdgcn_mfma_f32_16x16x32_bf16(af, bf, acc[fn], 0, 0, 0);
      }
    }
  };

  // Phase B: scores = q @ k^T accumulated over 4 x 128-d chunks
  f32x4 sacc[4] = {};
  for (int kc = 0; kc < 4; ++kc) {
    __syncthreads();                       // prior qlds/klds/wT readers done
    stageW(kc * 128);                      // wq chunk
    __syncthreads();
    {
      f32x4 qa[8] = {};
      gemm8(qa);
      #pragma unroll
      for (int fn = 0; fn < 8; ++fn) {
        float bias = sqb[kc*128 + fn*16 + ln15];
        #pragma unroll
        for (int j = 0; j < 4; ++j)
          qlds[w*16 + hi*4 + j][fn*16 + ln15] = f2bf(qa[fn][j] + bias);
      }
    }
    __syncthreads();                       // qlds visible; wT reads done
    stageW(512 + kc * 128);                // wk chunk
    __syncthreads();
    {
      f32x4 ka[8] = {};
      gemm8(ka);
      #pragma unroll
      for (int fn = 0; fn < 8; ++fn) {
        float bias = sqb[512 + kc*128 + fn*16 + ln15];
        #pragma unroll
        for (int j = 0; j < 4; ++j)
          klds[w*16 + hi*4 + j][fn*16 + ln15] = f2bf(ka[fn][j] + bias);
      }
    }
    __syncthreads();                       // klds visible
    #pragma unroll
    for (int kk = 0; kk < 4; ++kk) {
      s16x8 aq = *reinterpret_cast<const s16x8*>(&qlds[16*w + ln15][kk*32 + hi*8]);
      #pragma unroll
      for (int fn = 0; fn < 4; ++fn) {
        s16x8 bk = *reinterpret_cast<const s16x8*>(&klds[fn*16 + ln15][kk*32 + hi*8]);
        sacc[fn] = __builtin_amdgcn_mfma_f32_16x16x32_bf16(aq, bk, sacc[fn], 0, 0, 0);
      }
    }
  }

  // softmax + post-softmax scale -> plds bf16
  {
    float scale = scale_p[0];
    #pragma unroll
    for (int j = 0; j < 4; ++j) {
      int row = 16*w + hi*4 + j;
      float pv[4];
      float mx = -1e30f;
      #pragma unroll
      for (int fn = 0; fn < 4; ++fn) {
        int col = fn*16 + ln15;
        pv[fn] = sacc[fn][j] + rb[col - row + 63];
        mx = fmaxf(mx, pv[fn]);
      }
      #pragma unroll
      for (int d = 1; d < 16; d <<= 1) mx = fmaxf(mx, __shfl_xor(mx, d));
      float sum = 0.f;
      #pragma unroll
      for (int fn = 0; fn < 4; ++fn) { pv[fn] = __expf(pv[fn] - mx); sum += pv[fn]; }
      #pragma unroll
      for (int d = 1; d < 16; d <<= 1) sum += __shfl_xor(sum, d);
      float inv = scale / sum;
      #pragma unroll
      for (int fn = 0; fn < 4; ++fn) plds[row][fn*16 + ln15] = f2bf(pv[fn] * inv);
    }
  }

  // Phase D: per 128-col chunk: v -> vlds^T -> av = P@V -> proj += av @ pw
  f32x4 pracc[16] = {};
  for (int cc = 0; cc < 4; ++cc) {
    __syncthreads();                       // prior pwT/avl/wT readers done
    stageW(1024 + cc * 128);               // wv chunk -> wT
    stagePW(cc);                           // pw chunk -> pwT (disjoint region)
    __syncthreads();
    {
      f32x4 va[8] = {};
      gemm8(va);
      #pragma unroll
      for (int fn = 0; fn < 8; ++fn) {
        float bias = sqb[1024 + cc*128 + fn*16 + ln15];
        s16x4 vv;
        #pragma unroll
        for (int j = 0; j < 4; ++j) vv[j] = f2bf(va[fn][j] + bias);
        *reinterpret_cast<s16x4*>(&vlds[fn*16 + ln15][w*16 + hi*4]) = vv;  // transposed
      }
    }
    __syncthreads();                       // vlds visible
    f32x4 pacc[8] = {};
    #pragma unroll
    for (int kk = 0; kk < 2; ++kk) {
      s16x8 ap = *reinterpret_cast<const s16x8*>(&plds[16*w + ln15][kk*32 + hi*8]);
      #pragma unroll
      for (int fn = 0; fn < 8; ++fn) {
        s16x8 bv = *reinterpret_cast<const s16x8*>(&vlds[fn*16 + ln15][kk*32 + hi*8]);
        pacc[fn] = __builtin_amdgcn_mfma_f32_16x16x32_bf16(ap, bv, pacc[fn], 0, 0, 0);
      }
    }
    __syncthreads();                       // vlds reads done -> reuse as avl
    #pragma unroll
    for (int fn = 0; fn < 8; ++fn)
      #pragma unroll
      for (int j = 0; j < 4; ++j)
        avl[w*16 + hi*4 + j][fn*16 + ln15] = f2bf(pacc[fn][j]);
    __syncthreads();                       // avl visible
    #pragma unroll
    for (int kk = 0; kk < 4; ++kk) {
      s16x8 aa = *reinterpret_cast<const s16x8*>(&avl[16*w + ln15][kk*32 + hi*8]);
      const int o = kk*4 + hi;
      #pragma unroll
      for (int fn = 0; fn < 16; ++fn) {
        int col = fn*16 + ln15;
        int os = (o & 8) | ((o & 7) ^ (col & 7));
        s16x8 pb = *reinterpret_cast<const s16x8*>(&pwT[col][os * 8]);
        pracc[fn] = __builtin_amdgcn_mfma_f32_16x16x32_bf16(aa, pb, pracc[fn], 0, 0, 0);
      }
    }
  }

  // proj epilogue: +pb, LN over 256 (cross-lane within 16-lane group), -> ab f32
  #pragma unroll
  for (int j = 0; j < 4; ++j) {
    int row = 16*w + hi*4 + j;
    float vv[16];
    float s = 0.f, sq = 0.f;
    #pragma unroll
    for (int fn = 0; fn < 16; ++fn) {
      vv[fn] = pracc[fn][j] + s_apb[fn*16 + ln15];
      s += vv[fn]; sq += vv[fn]*vv[fn];
    }
    #pragma unroll
    for (int d = 1; d < 16; d <<= 1) { s += __shfl_xor(s, d); sq += __shfl_xor(sq, d); }
    float m = s * (1.f/256.f);
    float rstd = rsqrtf(sq*(1.f/256.f) - m*m + 1e-5f);
    #pragma unroll
    for (int fn = 0; fn < 16; ++fn) {
      int col = fn*16 + ln15;
      ab[((size_t)b*64 + row)*256 + col] = (vv[fn]-m)*rstd*s_ag[col] + s_ab2[col];
    }
  }
}

// ---------------------------------------------------------------------------
// Generic bf16-MFMA GEMM for the small GEMMs.
// EPI: 2 = gelu split u/v (pin); 3 = f32 out (+bias +res)
// ---------------------------------------------------------------------------
template<int BM, int BN, int WM, int WN, int EPI>
__global__ __launch_bounds__(256) void gemm_k(
    const short* __restrict__ A, const float* __restrict__ Bw,
    const float* __restrict__ bias, const float* __restrict__ res,
    void* __restrict__ O0, void* __restrict__ O1,
    int M, int N, int K, int Nreal, int Kreal)
{
  constexpr int BK = 64;
  __shared__ __align__(16) short As[BM][BK + 8];
  __shared__ __align__(16) short Bs[BN][BK + 8];
  const int t = threadIdx.x;
  const int lane = t & 63;
  const int w = t >> 6;
  const int wm = w / WN, wn = w % WN;
  const int ln15 = lane & 15, hi = lane >> 4;
  const int m0 = blockIdx.y * BM;
  const int n0 = blockIdx.x * BN;

  f32x4 acc[4][4] = {};

  for (int k0 = 0; k0 < K; k0 += BK) {
    #pragma unroll
    for (int i = 0; i < (BM*BK)/(256*8); ++i) {
      int e = (i*256 + t) * 8;
      int r = e / BK, c = e % BK;
      *reinterpret_cast<i32x4*>(&As[r][c]) =
          *reinterpret_cast<const i32x4*>(&A[(size_t)(m0 + r) * K + k0 + c]);
    }
    #pragma unroll
    for (int i = 0; i < (BK*BN)/256; ++i) {
      int idx = i*256 + t;
      int n = idx % BN, k = idx / BN;
      int gk = k0 + k, gn = n0 + n;
      float v = (gk < Kreal && gn < Nreal) ? Bw[(size_t)gk * Nreal + gn] : 0.f;
      Bs[n][k] = f2bf(v);
    }
    __syncthreads();
    #pragma unroll
    for (int kk = 0; kk < BK; kk += 32) {
      s16x8 af[4], bfr[4];
      #pragma unroll
      for (int fm = 0; fm < 4; ++fm)
        af[fm] = *reinterpret_cast<const s16x8*>(&As[wm*64 + fm*16 + ln15][kk + hi*8]);
      #pragma unroll
      for (int fn = 0; fn < 4; ++fn)
        bfr[fn] = *reinterpret_cast<const s16x8*>(&Bs[wn*64 + fn*16 + ln15][kk + hi*8]);
      #pragma unroll
      for (int fm = 0; fm < 4; ++fm)
        #pragma unroll
        for (int fn = 0; fn < 4; ++fn)
          acc[fm][fn] = __builtin_amdgcn_mfma_f32_16x16x32_bf16(
              af[fm], bfr[fn], acc[fm][fn], 0, 0, 0);
    }
    __syncthreads();
  }

  #pragma unroll
  for (int fm = 0; fm < 4; ++fm) {
    #pragma unroll
    for (int fn = 0; fn < 4; ++fn) {
      #pragma unroll
      for (int j = 0; j < 4; ++j) {
        int row = m0 + wm*64 + fm*16 + hi*4 + j;
        int col = n0 + wn*64 + fn*16 + ln15;
        float v = acc[fm][fn][j];
        if constexpr (EPI == 2) {
          v = gelu_f(v + bias[col]);
          if (col < 256) ((float*)O0)[(size_t)row * 256 + col] = v;
          else ((short*)O1)[(size_t)row * 256 + (col - 256)] = f2bf(v);
        } else { // 3
          v += bias[col] + res[(size_t)row * N + col];
          ((float*)O0)[(size_t)row * N + col] = v;
        }
      }
    }
  }
}

// ---------------------------------------------------------------------------
// K3: LayerNorm over 8192 (mlp_ln) -> bf16, TILE-PACKED output
// ---------------------------------------------------------------------------
__global__ __launch_bounds__(256) void ln8192_k(
    const float* __restrict__ x1,
    const float* __restrict__ g, const float* __restrict__ bb,
    short* __restrict__ lnxp)
{
  __shared__ float red[8];
  int t = threadIdx.x, w = t >> 6, lane = t & 63;
  int b = blockIdx.x;
  const f32x4* xr = reinterpret_cast<const f32x4*>(x1 + (size_t)b * 8192);
  f32x4 vals[8];
  float s = 0.f, sq = 0.f;
  #pragma unroll
  for (int i = 0; i < 8; ++i) {
    f32x4 v = xr[t + i*256];
    vals[i] = v;
    s  += v[0]+v[1]+v[2]+v[3];
    sq += v[0]*v[0]+v[1]*v[1]+v[2]*v[2]+v[3]*v[3];
  }
  s = waveSum(s); sq = waveSum(sq);
  if (lane == 0) { red[w] = s; red[4+w] = sq; }
  __syncthreads();
  s  = red[0]+red[1]+red[2]+red[3];
  sq = red[4]+red[5]+red[6]+red[7];
  float m = s * (1.f/8192.f);
  float rstd = rsqrtf(sq * (1.f/8192.f) - m*m + 1e-5f);
  #pragma unroll
  for (int i = 0; i < 8; ++i) {
    int idx = (t + i*256) * 4;
    f32x4 g4 = reinterpret_cast<const f32x4*>(g)[t + i*256];
    f32x4 b4 = reinterpret_cast<const f32x4*>(bb)[t + i*256];
    s16x4 o;
    #pragma unroll
    for (int k = 0; k < 4; ++k) o[k] = f2bf((vals[i][k]-m)*rstd*g4[k] + b4[k]);
    size_t paddr = ((size_t)(idx >> 6) * 512 + b) * 64 + (idx & 63);
    *reinterpret_cast<s16x4*>(&lnxp[paddr]) = o;
  }
}

// ---------------------------------------------------------------------------
// Split-K GEMM v9 (unchanged): tile-packed A, B dbuf LDS w/ XOR swizzle,
// write-early/load-late, soft barriers.
// ---------------------------------------------------------------------------
__global__ __launch_bounds__(512, 2) void gemm_splitk9(
    const short* __restrict__ Ap, const float* __restrict__ Bw,
    float* __restrict__ part,
    int N, int K, int Kreal, int ldb, int kchunk, int ntiles)
{
  __shared__ __align__(16) short Bs[2][128 * 64];
  const int t = threadIdx.x, lane = t & 63, w = t >> 6;
  const int ln15 = lane & 15, hi = lane >> 4;
  const int nt = blockIdx.x % ntiles, z = blockIdx.x / ntiles;
  const int n0 = nt * 128;
  const int kbeg = z * kchunk;
  const int kend = (kbeg + kchunk < K) ? (kbeg + kchunk) : K;
  const int nsteps = (kend - kbeg) >> 6;

  const int bn = t & 127;
  const int bg0 = (t >> 7) * 2;
  const bool bok = (n0 + bn) < ldb;
  const int bsw = bn & 7;

  float br[16];
  auto loadB = [&](int k0) {
    const float* bp = Bw + (size_t)(k0 + bg0 * 8) * ldb + n0 + bn;
    #pragma unroll
    for (int m = 0; m < 16; ++m) {
      int gk = k0 + bg0 * 8 + m;
      br[m] = (bok && gk < Kreal) ? bp[(size_t)m * ldb] : 0.f;
    }
  };
  auto writeB = [&](int buf) {
    s16x8 v0, v1;
    #pragma unroll
    for (int m = 0; m < 8; ++m) { v0[m] = f2bf(br[m]); v1[m] = f2bf(br[8 + m]); }
    short* dst = &Bs[buf][bn * 64];
    *reinterpret_cast<s16x8*>(dst + ((bg0    ) ^ bsw) * 8) = v0;
    *reinterpret_cast<s16x8*>(dst + ((bg0 + 1) ^ bsw) * 8) = v1;
  };

  f32x4 acc[4][8] = {};

  loadB(kbeg);
  writeB(0);
  if (nsteps > 1) loadB(kbeg + 64);
  softBarrier();

  for (int s = 0; s < nsteps; ++s) {
    const int k0 = kbeg + s * 64;
    const short* atile = Ap + (size_t)(k0 >> 6) * 512 * 64;
    s16x8 af[8];
    #pragma unroll
    for (int kk = 0; kk < 2; ++kk)
      #pragma unroll
      for (int fm = 0; fm < 4; ++fm) {
        int row = w * 64 + fm * 16 + ln15;
        af[kk * 4 + fm] = *reinterpret_cast<const s16x8*>(
            &atile[row * 64 + (kk * 4 + hi) * 8]);
      }
    if (s + 1 < nsteps) writeB((s + 1) & 1);
    if (s + 2 < nsteps) loadB(kbeg + (s + 2) * 64);

    const short* bsrc = &Bs[s & 1][0];
    #pragma unroll
    for (int kk = 0; kk < 2; ++kk) {
      const int g = kk * 4 + hi;
      #pragma unroll
      for (int fn = 0; fn < 8; ++fn) {
        int row = fn * 16 + ln15;
        s16x8 bv = *reinterpret_cast<const s16x8*>(
            &bsrc[row * 64 + ((g ^ (row & 7)) * 8)]);
        #pragma unroll
        for (int fm = 0; fm < 4; ++fm)
          acc[fm][fn] = __builtin_amdgcn_mfma_f32_16x16x32_bf16(
              af[kk * 4 + fm], bv, acc[fm][fn], 0, 0, 0);
      }
    }
    softBarrier();
  }

  #pragma unroll
  for (int fm = 0; fm < 4; ++fm)
    #pragma unroll
    for (int fn = 0; fn < 8; ++fn)
      #pragma unroll
      for (int j = 0; j < 4; ++j) {
        int row = w * 64 + fm * 16 + hi * 4 + j;
        int col = n0 + fn * 16 + ln15;
        part[((size_t)z * 512 + row) * N + col] = acc[fm][fn][j];
      }
}

// ---------------------------------------------------------------------------
// split-K reduce for mlp1: h3 = gelu(sum part + b1), bf16, TILE-PACKED out
// ---------------------------------------------------------------------------
__global__ __launch_bounds__(256) void reduce_mlp1_k(
    const float* __restrict__ part, const float* __restrict__ bias,
    short* __restrict__ h3p, int N, int Nreal, int M, int ks)
{
  int col4 = (blockIdx.x * 256 + threadIdx.x) * 4;
  int row = blockIdx.y;
  if (col4 >= N) return;
  size_t base = (size_t)row * N + col4;
  size_t stride = (size_t)M * N;
  f32x4 s = *reinterpret_cast<const f32x4*>(part + base);
  for (int k = 1; k < ks; ++k)
    s += *reinterpret_cast<const f32x4*>(part + base + (size_t)k * stride);
  s16x4 o;
  #pragma unroll
  for (int j = 0; j < 4; ++j) {
    int c = col4 + j;
    float v = 0.f;
    if (c < Nreal) v = gelu_f(s[j] + bias[c]);
    o[j] = f2bf(v);
  }
  size_t paddr = ((size_t)(col4 >> 6) * 512 + row) * 64 + (col4 & 63);
  *reinterpret_cast<s16x4*>(&h3p[paddr]) = o;
}

// ---------------------------------------------------------------------------
// split-K reduce for mlp2: out = sum part + b2 + x1 (f32)
// ---------------------------------------------------------------------------
__global__ __launch_bounds__(256) void reduce_mlp2_k(
    const float* __restrict__ part, const float* __restrict__ bias,
    const float* __restrict__ x1, float* __restrict__ out, int N, int M, int ks)
{
  int col4 = (blockIdx.x * 256 + threadIdx.x) * 4;
  int row = blockIdx.y;
  size_t base = (size_t)row * N + col4;
  size_t stride = (size_t)M * N;
  f32x4 s = *reinterpret_cast<const f32x4*>(part + base);
  for (int k = 1; k < ks; ++k)
    s += *reinterpret_cast<const f32x4*>(part + base + (size_t)k * stride);
  f32x4 b4 = *reinterpret_cast<const f32x4*>(bias + col4);
  f32x4 r4 = *reinterpret_cast<const f32x4*>(x1 + base);
  #pragma unroll
  for (int j = 0; j < 4; ++j) s[j] += b4[j] + r4[j];
  *reinterpret_cast<f32x4*>(out + base) = s;
}

// ---------------------------------------------------------------------------
// K5: SGU gate (unchanged)
// ---------------------------------------------------------------------------
__global__ __launch_bounds__(256) void gate_k(
    const float* __restrict__ u, const short* __restrict__ vbf,
    const float* __restrict__ a,
    const float* __restrict__ spg_g, const float* __restrict__ spg_b,
    const float* __restrict__ spw, const float* __restrict__ spb,
    const float* __restrict__ pog, const float* __restrict__ pob,
    short* __restrict__ outn)
{
  __shared__ __align__(16) short nvb[256][72];
  __shared__ __align__(16) short spwT[64][72];
  __shared__ float s_spg[64], s_spbl[64], s_spb[64];
  __shared__ float s_pog[256], s_pob[256];
  int t = threadIdx.x, lane = t & 63, w = t >> 6;
  int ln15 = lane & 15, hi = lane >> 4;
  int b = blockIdx.x;

  if (t < 64) { s_spg[t] = spg_g[t]; s_spbl[t] = spg_b[t]; s_spb[t] = spb[t]; }
  s_pog[t] = pog[t]; s_pob[t] = pob[t];
  #pragma unroll
  for (int i = 0; i < 16; ++i) {
    int idx = i*256 + t;
    int sr = idx >> 6, tc = idx & 63;
    spwT[tc][sr] = f2bf(spw[idx]);
  }

  float vvv[64];
  {
    int c = t;
    float s = 0.f, sq = 0.f;
    #pragma unroll
    for (int si = 0; si < 64; ++si) {
      float f = bf2f(vbf[(size_t)(b*64 + si) * 256 + c]);
      vvv[si] = f; s += f; sq += f*f;
    }
    float m = s * (1.f/64.f);
    float rstd = rsqrtf(sq * (1.f/64.f) - m*m + 1e-5f);
    __syncthreads();
    #pragma unroll
    for (int si = 0; si < 64; ++si)
      nvb[c][si] = f2bf((vvv[si]-m)*rstd*s_spg[si] + s_spbl[si]);
  }
  __syncthreads();

  f32x4 yacc[4][4] = {};
  #pragma unroll
  for (int kk = 0; kk < 64; kk += 32) {
    s16x8 af[4], bfr[4];
    #pragma unroll
    for (int fm = 0; fm < 4; ++fm)
      af[fm] = *reinterpret_cast<const s16x8*>(&nvb[64*w + fm*16 + ln15][kk + hi*8]);
    #pragma unroll
    for (int fn = 0; fn < 4; ++fn)
      bfr[fn] = *reinterpret_cast<const s16x8*>(&spwT[fn*16 + ln15][kk + hi*8]);
    #pragma unroll
    for (int fm = 0; fm < 4; ++fm)
      #pragma unroll
      for (int fn = 0; fn < 4; ++fn)
        yacc[fm][fn] = __builtin_amdgcn_mfma_f32_16x16x32_bf16(
            af[fm], bfr[fn], yacc[fm][fn], 0, 0, 0);
  }
  __syncthreads();

  short (*outl)[264] = reinterpret_cast<short(*)[264]>(&nvb[0][0]);
  #pragma unroll
  for (int fm = 0; fm < 4; ++fm) {
    #pragma unroll
    for (int fn = 0; fn < 4; ++fn) {
      int crow = 64*w + fm*16 + hi*4;
      int tcol = fn*16 + ln15;
      f32x4 u4 = *reinterpret_cast<const f32x4*>(&u[(size_t)(b*64 + tcol)*256 + crow]);
      f32x4 a4 = *reinterpret_cast<const f32x4*>(&a[(size_t)(b*64 + tcol)*256 + crow]);
      #pragma unroll
      for (int j = 0; j < 4; ++j) {
        float g = gelu_f(yacc[fm][fn][j] + s_spb[tcol]);
        float o = u4[j] * (g + a4[j]);
        outl[tcol][crow + j] = f2bf(o);
      }
    }
  }
  __syncthreads();

  #pragma unroll
  for (int ri = 0; ri < 16; ++ri) {
    int trow = w*16 + ri;
    int c = lane * 4;
    s16x4 raw = *reinterpret_cast<const s16x4*>(&outl[trow][c]);
    float f0 = bf2f(raw[0]), f1 = bf2f(raw[1]), f2 = bf2f(raw[2]), f3 = bf2f(raw[3]);
    float s  = f0+f1+f2+f3;
    float sq = f0*f0+f1*f1+f2*f2+f3*f3;
    s = waveSum(s); sq = waveSum(sq);
    float m = s * (1.f/256.f);
    float rstd = rsqrtf(sq * (1.f/256.f) - m*m + 1e-5f);
    s16x4 o;
    o[0] = f2bf((f0-m)*rstd*s_pog[c+0] + s_pob[c+0]);
    o[1] = f2bf((f1-m)*rstd*s_pog[c+1] + s_pob[c+1]);
    o[2] = f2bf((f2-m)*rstd*s_pog[c+2] + s_pob[c+2]);
    o[3] = f2bf((f3-m)*rstd*s_pog[c+3] + s_pob[c+3]);
    *reinterpret_cast<s16x4*>(&outn[(size_t)(b*64 + trow)*256 + c]) = o;
  }
}

// ---------------------------------------------------------------------------
extern "C" void kernel_launch(void* const* d_in, const int* in_sizes, int n_in,
                              void* d_out, int out_size, void* d_ws, size_t ws_size,
                              hipStream_t stream)
{
  const float* x          = (const float*)d_in[0];
  const float* qkv_ln_g   = (const float*)d_in[1];
  const float* qkv_ln_b   = (const float*)d_in[2];
  const float* qkv_w      = (const float*)d_in[3];
  const float* qkv_b      = (const float*)d_in[4];
  const float* attn_pw    = (const float*)d_in[5];
  const float* attn_pb    = (const float*)d_in[6];
  const float* attn_ln_g  = (const float*)d_in[7];
  const float* attn_ln_b  = (const float*)d_in[8];
  const float* rel_bias   = (const float*)d_in[9];
  const float* scale      = (const float*)d_in[10];
  const float* pin_ln_g   = (const float*)d_in[11];
  const float* pin_ln_b   = (const float*)d_in[12];
  const float* pin_w      = (const float*)d_in[13];
  const float* pin_b      = (const float*)d_in[14];
  const float* sp_ln_g    = (const float*)d_in[15];
  const float* sp_ln_b    = (const float*)d_in[16];
  const float* sp_w       = (const float*)d_in[17];
  const float* sp_b       = (const float*)d_in[18];
  const float* pout_ln_g  = (const float*)d_in[19];
  const float* pout_ln_b  = (const float*)d_in[20];
  const float* pout_w     = (const float*)d_in[21];
  const float* pout_b     = (const float*)d_in[22];
  const float* mlp_ln_g   = (const float*)d_in[23];
  const float* mlp_ln_b   = (const float*)d_in[24];
  const float* mlp_w1     = (const float*)d_in[25];
  const float* mlp_b1     = (const float*)d_in[26];
  const float* mlp_w2     = (const float*)d_in[27];
  const float* mlp_b2     = (const float*)d_in[28];

  char* ws = (char*)d_ws;
  short* lnp   = (short*)(ws + 0);           // 8.39 MB (dead after pin gemm)
  float* x1b   = (float*)(ws + 0);           // 16.78 MB (written at pout)
  float* ab    = (float*)(ws + 16777216);    // 33.55 MB f32
  float* ub    = (float*)(ws + 50331648);    // 33.55 MB f32
  short* vbfb  = (short*)(ws + 83886080);    // 16.78 MB bf16
  short* outnb = (short*)(ws + 100663296);   // 16.78 MB bf16
  short* lnxp  = (short*)(ws + 150994944);   // 8.39 MB (tile-packed)
  short* h3p   = (short*)(ws + 159383552);   // 9.31 MB (tile-packed)
  float* partb = (float*)(ws + 16777216);    // split-K partials (<=74.5 MB,
                                             // aliases ab/ub/vbf/outn region)

  // fused: LN + qkv + attention + proj + ln256  ->  lnp, ab
  fused_attn_k<<<512, 256, 0, stream>>>(
      x, qkv_ln_g, qkv_ln_b, pin_ln_g, pin_ln_b, qkv_w, qkv_b,
      attn_pw, attn_pb, attn_ln_g, attn_ln_b, rel_bias, scale, lnp, ab);
  // pin: [32768,128]@[128,512]+b, gelu, split u (f32) / v (bf16)
  gemm_k<128,128,2,2,2><<<dim3(4,256), 256, 0, stream>>>(
      lnp, pin_w, pin_b, nullptr, ub, vbfb, 32768, 512, 128, 512, 128);
  // SGU gate + fused pout_ln -> outn bf16
  gate_k<<<512, 256, 0, stream>>>(ub, vbfb, ab, sp_ln_g, sp_ln_b, sp_w, sp_b,
                                  pout_ln_g, pout_ln_b, outnb);
  // pout: [32768,256]@[256,128]+b + x residual -> x1 f32
  gemm_k<128,128,2,2,3><<<dim3(1,256), 256, 0, stream>>>(
      outnb, pout_w, pout_b, x, x1b, nullptr, 32768, 128, 256, 128, 256);
  // LN over 8192 -> lnx (tile-packed)
  ln8192_k<<<512, 256, 0, stream>>>(x1b, mlp_ln_g, mlp_ln_b, lnxp);

  // mlp1: [512,8192] @ [8192,9011] (N padded 9088), split-K 3, 213 blocks
  gemm_splitk9<<<213, 512, 0, stream>>>(
      lnxp, mlp_w1, partb, /*N=*/9088, /*K=*/8192, /*Kreal=*/8192,
      /*ldb=*/9011, /*kchunk=*/2752, /*ntiles=*/71);
  reduce_mlp1_k<<<dim3(9, 512), 256, 0, stream>>>(partb, mlp_b1, h3p, 9088, 9011, 512, 3);

  // mlp2: [512,9088] @ [9011,8192], split-K 4, 256 blocks
  gemm_splitk9<<<256, 512, 0, stream>>>(
      h3p, mlp_w2, partb, /*N=*/8192, /*K=*/9088, /*Kreal=*/9011,
      /*ldb=*/8192, /*kchunk=*/2304, /*ntiles=*/64);
  reduce_mlp2_k<<<dim3(8, 512), 256, 0, stream>>>(partb, mlp_b2, x1b, (float*)d_out, 8192, 512, 4);
}

// Round 13
// 649.488 us; speedup vs baseline: 1.3571x; 1.1064x over previous
//
#include <hip/hip_runtime.h>
#include <hip/hip_bf16.h>
#include <math.h>

typedef float f32x4 __attribute__((ext_vector_type(4)));
typedef float f32x2 __attribute__((ext_vector_type(2)));
typedef short s16x8 __attribute__((ext_vector_type(8)));
typedef short s16x4 __attribute__((ext_vector_type(4)));
typedef int   i32x4 __attribute__((ext_vector_type(4)));

__device__ __forceinline__ short f2bf(float f) {
  __hip_bfloat16 h = __float2bfloat16(f);
  return __builtin_bit_cast(short, h);
}
__device__ __forceinline__ float bf2f(short s) {
  __hip_bfloat16 h = __builtin_bit_cast(__hip_bfloat16, s);
  return __bfloat162float(h);
}
__device__ __forceinline__ float gelu_f(float x) {
  return 0.5f * x * (1.f + erff(x * 0.70710678118654752440f));
}
__device__ __forceinline__ float waveSum(float v) {
  #pragma unroll
  for (int d = 32; d; d >>= 1) v += __shfl_xor(v, d);
  return v;
}
// Soft barrier: LDS-visibility only; does NOT drain vmcnt.
__device__ __forceinline__ void softBarrier() {
  asm volatile("s_waitcnt lgkmcnt(0)" ::: "memory");
  __builtin_amdgcn_s_barrier();
  asm volatile("" ::: "memory");
}

// ---------------------------------------------------------------------------
// P0: one-shot weight transpose to bf16.
// wTg[1536][128]  = qkv_w^T   (row = output col, 128 k each)
// pwTg[256][512]  = attn_pw^T (row = output col, 512 k each)
// ---------------------------------------------------------------------------
__global__ __launch_bounds__(256) void prep_w_k(
    const float* __restrict__ qkv_w, const float* __restrict__ attn_pw,
    short* __restrict__ wTg, short* __restrict__ pwTg)
{
  int idx = blockIdx.x * 256 + threadIdx.x;
  if (idx < 24576) {                 // 1536*128/8
    int r = idx >> 4;
    int k0 = (idx & 15) * 8;
    s16x8 v;
    #pragma unroll
    for (int m = 0; m < 8; ++m) v[m] = f2bf(qkv_w[(size_t)(k0 + m) * 1536 + r]);
    *reinterpret_cast<s16x8*>(&wTg[r * 128 + k0]) = v;
  } else if (idx < 24576 + 16384) {  // 256*512/8
    int e = idx - 24576;
    int r = e >> 6;
    int k0 = (e & 63) * 8;
    s16x8 v;
    #pragma unroll
    for (int m = 0; m < 8; ++m) v[m] = f2bf(attn_pw[(size_t)(k0 + m) * 256 + r]);
    *reinterpret_cast<s16x8*>(&pwTg[r * 512 + k0]) = v;
  }
}

// ---------------------------------------------------------------------------
// F1 v3: fused per-board attention branch; weights read as MFMA B-fragments
// DIRECTLY from the pre-transposed global buffers (L2-resident) -- no weight
// LDS staging at all.  LDS = 71.5 KB -> 2 blocks/CU (R12 was 153 KB -> 1).
// q,k computed in 64-col chunks (q64/k64), v/proj in 128-col chunks.
// MFMA conventions identical to R11/R12 (verified passing).
// ---------------------------------------------------------------------------
__global__ __launch_bounds__(256, 2) void fused_attn_k(
    const float* __restrict__ x,
    const float* __restrict__ qln_g, const float* __restrict__ qln_b,
    const float* __restrict__ pln_g, const float* __restrict__ pln_b,
    const short* __restrict__ wTg, const float* __restrict__ qkv_b,
    const short* __restrict__ pwTg, const float* __restrict__ attn_pb,
    const float* __restrict__ aln_g, const float* __restrict__ aln_b,
    const float* __restrict__ relb, const float* __restrict__ scale_p,
    short* __restrict__ lnp, float* __restrict__ ab)
{
  __shared__ __align__(16) char arena[73216];
  short (*lnq)[136] = reinterpret_cast<short(*)[136]>(arena + 0);      // 17408
  short (*vlds)[72] = reinterpret_cast<short(*)[72]>(arena + 17408);   // 18432
  short (*avl)[136] = reinterpret_cast<short(*)[136]>(arena + 17408);  // alias
  short (*q64)[72]  = reinterpret_cast<short(*)[72]>(arena + 35840);   // 9216
  short (*k64)[72]  = reinterpret_cast<short(*)[72]>(arena + 45056);   // 9216
  short (*p64)[72]  = reinterpret_cast<short(*)[72]>(arena + 54272);   // 9216
  float* sqb  = reinterpret_cast<float*>(arena + 63488);  // 1536 f32
  float* rb   = reinterpret_cast<float*>(arena + 69632);  // 127 f32
  float* sapb = reinterpret_cast<float*>(arena + 70144);  // 256
  float* sag  = reinterpret_cast<float*>(arena + 71168);  // 256
  float* sab2 = reinterpret_cast<float*>(arena + 72192);  // 256

  const int t = threadIdx.x, lane = t & 63, w = t >> 6;
  const int ln15 = lane & 15, hi = lane >> 4;
  const int b = blockIdx.x;

  if (t < 127) rb[t] = relb[t];
  sapb[t] = attn_pb[t]; sag[t] = aln_g[t]; sab2[t] = aln_b[t];
  #pragma unroll
  for (int i = 0; i < 6; ++i) sqb[i*256 + t] = qkv_b[i*256 + t];

  // Phase A: row LN -> lnq (LDS bf16) and lnp (global bf16)
  {
    int c = lane * 2;
    float qg0 = qln_g[c], qg1 = qln_g[c+1], qb0 = qln_b[c], qb1 = qln_b[c+1];
    float pg0 = pln_g[c], pg1 = pln_g[c+1], pb0 = pln_b[c], pb1 = pln_b[c+1];
    for (int i = 0; i < 16; ++i) {
      int r = w * 16 + i;
      f32x2 v = *reinterpret_cast<const f32x2*>(&x[((size_t)b*64 + r)*128 + c]);
      float s = v[0] + v[1], sq = v[0]*v[0] + v[1]*v[1];
      s = waveSum(s); sq = waveSum(sq);
      float m = s * (1.f/128.f);
      float rstd = rsqrtf(sq*(1.f/128.f) - m*m + 1e-5f);
      float a0 = (v[0]-m)*rstd, a1 = (v[1]-m)*rstd;
      unsigned u0 = (unsigned short)f2bf(a0*qg0 + qb0);
      unsigned u1 = (unsigned short)f2bf(a1*qg1 + qb1);
      *reinterpret_cast<unsigned*>(&lnq[r][c]) = u0 | (u1 << 16);
      unsigned p0 = (unsigned short)f2bf(a0*pg0 + pb0);
      unsigned p1 = (unsigned short)f2bf(a1*pg1 + pb1);
      ((unsigned*)lnp)[((size_t)b*64 + r)*64 + lane] = p0 | (p1 << 16);
    }
  }
  __syncthreads();

  // out(64 x 64chunk) = lnq @ wTg[coff.. ] : B-frags direct from global
  auto gemm4g = [&](int coff, f32x4 (&acc)[4]) {
    #pragma unroll
    for (int kk = 0; kk < 4; ++kk) {
      s16x8 af = *reinterpret_cast<const s16x8*>(&lnq[w*16 + ln15][kk*32 + hi*8]);
      #pragma unroll
      for (int fn = 0; fn < 4; ++fn) {
        int col = coff + fn*16 + ln15;
        s16x8 bf = *reinterpret_cast<const s16x8*>(&wTg[(size_t)col*128 + kk*32 + hi*8]);
        acc[fn] = __builtin_amdgcn_mfma_f32_16x16x32_bf16(af, bf, acc[fn], 0, 0, 0);
      }
    }
  };
  auto gemm8g = [&](int coff, f32x4 (&acc)[8]) {
    #pragma unroll
    for (int kk = 0; kk < 4; ++kk) {
      s16x8 af = *reinterpret_cast<const s16x8*>(&lnq[w*16 + ln15][kk*32 + hi*8]);
      #pragma unroll
      for (int fn = 0; fn < 8; ++fn) {
        int col = coff + fn*16 + ln15;
        s16x8 bf = *reinterpret_cast<const s16x8*>(&wTg[(size_t)col*128 + kk*32 + hi*8]);
        acc[fn] = __builtin_amdgcn_mfma_f32_16x16x32_bf16(af, bf, acc[fn], 0, 0, 0);
      }
    }
  };

  // Phase B: scores = q @ k^T over 8 x 64-d chunks
  f32x4 sacc[4] = {};
  for (int kc = 0; kc < 8; ++kc) {
    __syncthreads();                   // q64/k64 overwrite vs prior QK reads
    f32x4 qa[4] = {};
    gemm4g(kc * 64, qa);
    #pragma unroll
    for (int fn = 0; fn < 4; ++fn) {
      float bias = sqb[kc*64 + fn*16 + ln15];
      #pragma unroll
      for (int j = 0; j < 4; ++j)
        q64[w*16 + hi*4 + j][fn*16 + ln15] = f2bf(qa[fn][j] + bias);
    }
    f32x4 ka[4] = {};
    gemm4g(512 + kc * 64, ka);
    #pragma unroll
    for (int fn = 0; fn < 4; ++fn) {
      float bias = sqb[512 + kc*64 + fn*16 + ln15];
      #pragma unroll
      for (int j = 0; j < 4; ++j)
        k64[w*16 + hi*4 + j][fn*16 + ln15] = f2bf(ka[fn][j] + bias);
    }
    __syncthreads();                   // q64/k64 visible
    #pragma unroll
    for (int kk = 0; kk < 2; ++kk) {
      s16x8 aq = *reinterpret_cast<const s16x8*>(&q64[16*w + ln15][kk*32 + hi*8]);
      #pragma unroll
      for (int fn = 0; fn < 4; ++fn) {
        s16x8 bk = *reinterpret_cast<const s16x8*>(&k64[fn*16 + ln15][kk*32 + hi*8]);
        sacc[fn] = __builtin_amdgcn_mfma_f32_16x16x32_bf16(aq, bk, sacc[fn], 0, 0, 0);
      }
    }
  }

  // softmax + post-softmax scale -> p64 bf16 (wave-local rows)
  {
    float scale = scale_p[0];
    #pragma unroll
    for (int j = 0; j < 4; ++j) {
      int row = 16*w + hi*4 + j;
      float pv[4];
      float mx = -1e30f;
      #pragma unroll
      for (int fn = 0; fn < 4; ++fn) {
        int col = fn*16 + ln15;
        pv[fn] = sacc[fn][j] + rb[col - row + 63];
        mx = fmaxf(mx, pv[fn]);
      }
      #pragma unroll
      for (int d = 1; d < 16; d <<= 1) mx = fmaxf(mx, __shfl_xor(mx, d));
      float sum = 0.f;
      #pragma unroll
      for (int fn = 0; fn < 4; ++fn) { pv[fn] = __expf(pv[fn] - mx); sum += pv[fn]; }
      #pragma unroll
      for (int d = 1; d < 16; d <<= 1) sum += __shfl_xor(sum, d);
      float inv = scale / sum;
      #pragma unroll
      for (int fn = 0; fn < 4; ++fn) p64[row][fn*16 + ln15] = f2bf(pv[fn] * inv);
    }
  }

  // Phase D: per 128-col chunk: v -> vlds^T -> av = P@V -> avl -> proj
  f32x4 pracc[16] = {};
  for (int cc = 0; cc < 4; ++cc) {
    __syncthreads();                   // vlds overwrite vs prior avl reads
    f32x4 va[8] = {};
    gemm8g(1024 + cc * 128, va);
    #pragma unroll
    for (int fn = 0; fn < 8; ++fn) {
      float bias = sqb[1024 + cc*128 + fn*16 + ln15];
      s16x4 vv;
      #pragma unroll
      for (int j = 0; j < 4; ++j) vv[j] = f2bf(va[fn][j] + bias);
      *reinterpret_cast<s16x4*>(&vlds[fn*16 + ln15][w*16 + hi*4]) = vv;  // transposed
    }
    __syncthreads();                   // vlds visible (p64 also)
    f32x4 pacc[8] = {};
    #pragma unroll
    for (int kk = 0; kk < 2; ++kk) {
      s16x8 ap = *reinterpret_cast<const s16x8*>(&p64[16*w + ln15][kk*32 + hi*8]);
      #pragma unroll
      for (int fn = 0; fn < 8; ++fn) {
        s16x8 bv = *reinterpret_cast<const s16x8*>(&vlds[fn*16 + ln15][kk*32 + hi*8]);
        pacc[fn] = __builtin_amdgcn_mfma_f32_16x16x32_bf16(ap, bv, pacc[fn], 0, 0, 0);
      }
    }
    __syncthreads();                   // vlds reads done -> reuse as avl
    #pragma unroll
    for (int fn = 0; fn < 8; ++fn)
      #pragma unroll
      for (int j = 0; j < 4; ++j)
        avl[w*16 + hi*4 + j][fn*16 + ln15] = f2bf(pacc[fn][j]);
    __syncthreads();                   // avl visible
    #pragma unroll
    for (int kk = 0; kk < 4; ++kk) {
      s16x8 aa = *reinterpret_cast<const s16x8*>(&avl[16*w + ln15][kk*32 + hi*8]);
      #pragma unroll
      for (int fn = 0; fn < 16; ++fn) {
        s16x8 pb = *reinterpret_cast<const s16x8*>(
            &pwTg[(size_t)(fn*16 + ln15)*512 + cc*128 + kk*32 + hi*8]);
        pracc[fn] = __builtin_amdgcn_mfma_f32_16x16x32_bf16(aa, pb, pracc[fn], 0, 0, 0);
      }
    }
  }

  // proj epilogue: +pb, LN over 256, -> ab f32
  #pragma unroll
  for (int j = 0; j < 4; ++j) {
    int row = 16*w + hi*4 + j;
    float vv[16];
    float s = 0.f, sq = 0.f;
    #pragma unroll
    for (int fn = 0; fn < 16; ++fn) {
      vv[fn] = pracc[fn][j] + sapb[fn*16 + ln15];
      s += vv[fn]; sq += vv[fn]*vv[fn];
    }
    #pragma unroll
    for (int d = 1; d < 16; d <<= 1) { s += __shfl_xor(s, d); sq += __shfl_xor(sq, d); }
    float m = s * (1.f/256.f);
    float rstd = rsqrtf(sq*(1.f/256.f) - m*m + 1e-5f);
    #pragma unroll
    for (int fn = 0; fn < 16; ++fn) {
      int col = fn*16 + ln15;
      ab[((size_t)b*64 + row)*256 + col] = (vv[fn]-m)*rstd*sag[col] + sab2[col];
    }
  }
}

// ---------------------------------------------------------------------------
// Generic bf16-MFMA GEMM for the small GEMMs.
// EPI: 2 = gelu split u/v (pin); 3 = f32 out (+bias +res)
// ---------------------------------------------------------------------------
template<int BM, int BN, int WM, int WN, int EPI>
__global__ __launch_bounds__(256) void gemm_k(
    const short* __restrict__ A, const float* __restrict__ Bw,
    const float* __restrict__ bias, const float* __restrict__ res,
    void* __restrict__ O0, void* __restrict__ O1,
    int M, int N, int K, int Nreal, int Kreal)
{
  constexpr int BK = 64;
  __shared__ __align__(16) short As[BM][BK + 8];
  __shared__ __align__(16) short Bs[BN][BK + 8];
  const int t = threadIdx.x;
  const int lane = t & 63;
  const int w = t >> 6;
  const int wm = w / WN, wn = w % WN;
  const int ln15 = lane & 15, hi = lane >> 4;
  const int m0 = blockIdx.y * BM;
  const int n0 = blockIdx.x * BN;

  f32x4 acc[4][4] = {};

  for (int k0 = 0; k0 < K; k0 += BK) {
    #pragma unroll
    for (int i = 0; i < (BM*BK)/(256*8); ++i) {
      int e = (i*256 + t) * 8;
      int r = e / BK, c = e % BK;
      *reinterpret_cast<i32x4*>(&As[r][c]) =
          *reinterpret_cast<const i32x4*>(&A[(size_t)(m0 + r) * K + k0 + c]);
    }
    #pragma unroll
    for (int i = 0; i < (BK*BN)/256; ++i) {
      int idx = i*256 + t;
      int n = idx % BN, k = idx / BN;
      int gk = k0 + k, gn = n0 + n;
      float v = (gk < Kreal && gn < Nreal) ? Bw[(size_t)gk * Nreal + gn] : 0.f;
      Bs[n][k] = f2bf(v);
    }
    __syncthreads();
    #pragma unroll
    for (int kk = 0; kk < BK; kk += 32) {
      s16x8 af[4], bfr[4];
      #pragma unroll
      for (int fm = 0; fm < 4; ++fm)
        af[fm] = *reinterpret_cast<const s16x8*>(&As[wm*64 + fm*16 + ln15][kk + hi*8]);
      #pragma unroll
      for (int fn = 0; fn < 4; ++fn)
        bfr[fn] = *reinterpret_cast<const s16x8*>(&Bs[wn*64 + fn*16 + ln15][kk + hi*8]);
      #pragma unroll
      for (int fm = 0; fm < 4; ++fm)
        #pragma unroll
        for (int fn = 0; fn < 4; ++fn)
          acc[fm][fn] = __builtin_amdgcn_mfma_f32_16x16x32_bf16(
              af[fm], bfr[fn], acc[fm][fn], 0, 0, 0);
    }
    __syncthreads();
  }

  #pragma unroll
  for (int fm = 0; fm < 4; ++fm) {
    #pragma unroll
    for (int fn = 0; fn < 4; ++fn) {
      #pragma unroll
      for (int j = 0; j < 4; ++j) {
        int row = m0 + wm*64 + fm*16 + hi*4 + j;
        int col = n0 + wn*64 + fn*16 + ln15;
        float v = acc[fm][fn][j];
        if constexpr (EPI == 2) {
          v = gelu_f(v + bias[col]);
          if (col < 256) ((float*)O0)[(size_t)row * 256 + col] = v;
          else ((short*)O1)[(size_t)row * 256 + (col - 256)] = f2bf(v);
        } else { // 3
          v += bias[col] + res[(size_t)row * N + col];
          ((float*)O0)[(size_t)row * N + col] = v;
        }
      }
    }
  }
}

// ---------------------------------------------------------------------------
// K3: LayerNorm over 8192 (mlp_ln) -> bf16, TILE-PACKED output
// ---------------------------------------------------------------------------
__global__ __launch_bounds__(256) void ln8192_k(
    const float* __restrict__ x1,
    const float* __restrict__ g, const float* __restrict__ bb,
    short* __restrict__ lnxp)
{
  __shared__ float red[8];
  int t = threadIdx.x, w = t >> 6, lane = t & 63;
  int b = blockIdx.x;
  const f32x4* xr = reinterpret_cast<const f32x4*>(x1 + (size_t)b * 8192);
  f32x4 vals[8];
  float s = 0.f, sq = 0.f;
  #pragma unroll
  for (int i = 0; i < 8; ++i) {
    f32x4 v = xr[t + i*256];
    vals[i] = v;
    s  += v[0]+v[1]+v[2]+v[3];
    sq += v[0]*v[0]+v[1]*v[1]+v[2]*v[2]+v[3]*v[3];
  }
  s = waveSum(s); sq = waveSum(sq);
  if (lane == 0) { red[w] = s; red[4+w] = sq; }
  __syncthreads();
  s  = red[0]+red[1]+red[2]+red[3];
  sq = red[4]+red[5]+red[6]+red[7];
  float m = s * (1.f/8192.f);
  float rstd = rsqrtf(sq * (1.f/8192.f) - m*m + 1e-5f);
  #pragma unroll
  for (int i = 0; i < 8; ++i) {
    int idx = (t + i*256) * 4;
    f32x4 g4 = reinterpret_cast<const f32x4*>(g)[t + i*256];
    f32x4 b4 = reinterpret_cast<const f32x4*>(bb)[t + i*256];
    s16x4 o;
    #pragma unroll
    for (int k = 0; k < 4; ++k) o[k] = f2bf((vals[i][k]-m)*rstd*g4[k] + b4[k]);
    size_t paddr = ((size_t)(idx >> 6) * 512 + b) * 64 + (idx & 63);
    *reinterpret_cast<s16x4*>(&lnxp[paddr]) = o;
  }
}

// ---------------------------------------------------------------------------
// Split-K GEMM v9 (unchanged): tile-packed A, B dbuf LDS w/ XOR swizzle,
// write-early/load-late, soft barriers.
// ---------------------------------------------------------------------------
__global__ __launch_bounds__(512, 2) void gemm_splitk9(
    const short* __restrict__ Ap, const float* __restrict__ Bw,
    float* __restrict__ part,
    int N, int K, int Kreal, int ldb, int kchunk, int ntiles)
{
  __shared__ __align__(16) short Bs[2][128 * 64];
  const int t = threadIdx.x, lane = t & 63, w = t >> 6;
  const int ln15 = lane & 15, hi = lane >> 4;
  const int nt = blockIdx.x % ntiles, z = blockIdx.x / ntiles;
  const int n0 = nt * 128;
  const int kbeg = z * kchunk;
  const int kend = (kbeg + kchunk < K) ? (kbeg + kchunk) : K;
  const int nsteps = (kend - kbeg) >> 6;

  const int bn = t & 127;
  const int bg0 = (t >> 7) * 2;
  const bool bok = (n0 + bn) < ldb;
  const int bsw = bn & 7;

  float br[16];
  auto loadB = [&](int k0) {
    const float* bp = Bw + (size_t)(k0 + bg0 * 8) * ldb + n0 + bn;
    #pragma unroll
    for (int m = 0; m < 16; ++m) {
      int gk = k0 + bg0 * 8 + m;
      br[m] = (bok && gk < Kreal) ? bp[(size_t)m * ldb] : 0.f;
    }
  };
  auto writeB = [&](int buf) {
    s16x8 v0, v1;
    #pragma unroll
    for (int m = 0; m < 8; ++m) { v0[m] = f2bf(br[m]); v1[m] = f2bf(br[8 + m]); }
    short* dst = &Bs[buf][bn * 64];
    *reinterpret_cast<s16x8*>(dst + ((bg0    ) ^ bsw) * 8) = v0;
    *reinterpret_cast<s16x8*>(dst + ((bg0 + 1) ^ bsw) * 8) = v1;
  };

  f32x4 acc[4][8] = {};

  loadB(kbeg);
  writeB(0);
  if (nsteps > 1) loadB(kbeg + 64);
  softBarrier();

  for (int s = 0; s < nsteps; ++s) {
    const int k0 = kbeg + s * 64;
    const short* atile = Ap + (size_t)(k0 >> 6) * 512 * 64;
    s16x8 af[8];
    #pragma unroll
    for (int kk = 0; kk < 2; ++kk)
      #pragma unroll
      for (int fm = 0; fm < 4; ++fm) {
        int row = w * 64 + fm * 16 + ln15;
        af[kk * 4 + fm] = *reinterpret_cast<const s16x8*>(
            &atile[row * 64 + (kk * 4 + hi) * 8]);
      }
    if (s + 1 < nsteps) writeB((s + 1) & 1);
    if (s + 2 < nsteps) loadB(kbeg + (s + 2) * 64);

    const short* bsrc = &Bs[s & 1][0];
    #pragma unroll
    for (int kk = 0; kk < 2; ++kk) {
      const int g = kk * 4 + hi;
      #pragma unroll
      for (int fn = 0; fn < 8; ++fn) {
        int row = fn * 16 + ln15;
        s16x8 bv = *reinterpret_cast<const s16x8*>(
            &bsrc[row * 64 + ((g ^ (row & 7)) * 8)]);
        #pragma unroll
        for (int fm = 0; fm < 4; ++fm)
          acc[fm][fn] = __builtin_amdgcn_mfma_f32_16x16x32_bf16(
              af[kk * 4 + fm], bv, acc[fm][fn], 0, 0, 0);
      }
    }
    softBarrier();
  }

  #pragma unroll
  for (int fm = 0; fm < 4; ++fm)
    #pragma unroll
    for (int fn = 0; fn < 8; ++fn)
      #pragma unroll
      for (int j = 0; j < 4; ++j) {
        int row = w * 64 + fm * 16 + hi * 4 + j;
        int col = n0 + fn * 16 + ln15;
        part[((size_t)z * 512 + row) * N + col] = acc[fm][fn][j];
      }
}

// ---------------------------------------------------------------------------
// split-K reduce for mlp1: h3 = gelu(sum part + b1), bf16, TILE-PACKED out
// ---------------------------------------------------------------------------
__global__ __launch_bounds__(256) void reduce_mlp1_k(
    const float* __restrict__ part, const float* __restrict__ bias,
    short* __restrict__ h3p, int N, int Nreal, int M, int ks)
{
  int col4 = (blockIdx.x * 256 + threadIdx.x) * 4;
  int row = blockIdx.y;
  if (col4 >= N) return;
  size_t base = (size_t)row * N + col4;
  size_t stride = (size_t)M * N;
  f32x4 s = *reinterpret_cast<const f32x4*>(part + base);
  for (int k = 1; k < ks; ++k)
    s += *reinterpret_cast<const f32x4*>(part + base + (size_t)k * stride);
  s16x4 o;
  #pragma unroll
  for (int j = 0; j < 4; ++j) {
    int c = col4 + j;
    float v = 0.f;
    if (c < Nreal) v = gelu_f(s[j] + bias[c]);
    o[j] = f2bf(v);
  }
  size_t paddr = ((size_t)(col4 >> 6) * 512 + row) * 64 + (col4 & 63);
  *reinterpret_cast<s16x4*>(&h3p[paddr]) = o;
}

// ---------------------------------------------------------------------------
// split-K reduce for mlp2: out = sum part + b2 + x1 (f32)
// ---------------------------------------------------------------------------
__global__ __launch_bounds__(256) void reduce_mlp2_k(
    const float* __restrict__ part, const float* __restrict__ bias,
    const float* __restrict__ x1, float* __restrict__ out, int N, int M, int ks)
{
  int col4 = (blockIdx.x * 256 + threadIdx.x) * 4;
  int row = blockIdx.y;
  size_t base = (size_t)row * N + col4;
  size_t stride = (size_t)M * N;
  f32x4 s = *reinterpret_cast<const f32x4*>(part + base);
  for (int k = 1; k < ks; ++k)
    s += *reinterpret_cast<const f32x4*>(part + base + (size_t)k * stride);
  f32x4 b4 = *reinterpret_cast<const f32x4*>(bias + col4);
  f32x4 r4 = *reinterpret_cast<const f32x4*>(x1 + base);
  #pragma unroll
  for (int j = 0; j < 4; ++j) s[j] += b4[j] + r4[j];
  *reinterpret_cast<f32x4*>(out + base) = s;
}

// ---------------------------------------------------------------------------
// K5: SGU gate (unchanged)
// ---------------------------------------------------------------------------
__global__ __launch_bounds__(256) void gate_k(
    const float* __restrict__ u, const short* __restrict__ vbf,
    const float* __restrict__ a,
    const float* __restrict__ spg_g, const float* __restrict__ spg_b,
    const float* __restrict__ spw, const float* __restrict__ spb,
    const float* __restrict__ pog, const float* __restrict__ pob,
    short* __restrict__ outn)
{
  __shared__ __align__(16) short nvb[256][72];
  __shared__ __align__(16) short spwT[64][72];
  __shared__ float s_spg[64], s_spbl[64], s_spb[64];
  __shared__ float s_pog[256], s_pob[256];
  int t = threadIdx.x, lane = t & 63, w = t >> 6;
  int ln15 = lane & 15, hi = lane >> 4;
  int b = blockIdx.x;

  if (t < 64) { s_spg[t] = spg_g[t]; s_spbl[t] = spg_b[t]; s_spb[t] = spb[t]; }
  s_pog[t] = pog[t]; s_pob[t] = pob[t];
  #pragma unroll
  for (int i = 0; i < 16; ++i) {
    int idx = i*256 + t;
    int sr = idx >> 6, tc = idx & 63;
    spwT[tc][sr] = f2bf(spw[idx]);
  }

  float vvv[64];
  {
    int c = t;
    float s = 0.f, sq = 0.f;
    #pragma unroll
    for (int si = 0; si < 64; ++si) {
      float f = bf2f(vbf[(size_t)(b*64 + si) * 256 + c]);
      vvv[si] = f; s += f; sq += f*f;
    }
    float m = s * (1.f/64.f);
    float rstd = rsqrtf(sq * (1.f/64.f) - m*m + 1e-5f);
    __syncthreads();
    #pragma unroll
    for (int si = 0; si < 64; ++si)
      nvb[c][si] = f2bf((vvv[si]-m)*rstd*s_spg[si] + s_spbl[si]);
  }
  __syncthreads();

  f32x4 yacc[4][4] = {};
  #pragma unroll
  for (int kk = 0; kk < 64; kk += 32) {
    s16x8 af[4], bfr[4];
    #pragma unroll
    for (int fm = 0; fm < 4; ++fm)
      af[fm] = *reinterpret_cast<const s16x8*>(&nvb[64*w + fm*16 + ln15][kk + hi*8]);
    #pragma unroll
    for (int fn = 0; fn < 4; ++fn)
      bfr[fn] = *reinterpret_cast<const s16x8*>(&spwT[fn*16 + ln15][kk + hi*8]);
    #pragma unroll
    for (int fm = 0; fm < 4; ++fm)
      #pragma unroll
      for (int fn = 0; fn < 4; ++fn)
        yacc[fm][fn] = __builtin_amdgcn_mfma_f32_16x16x32_bf16(
            af[fm], bfr[fn], yacc[fm][fn], 0, 0, 0);
  }
  __syncthreads();

  short (*outl)[264] = reinterpret_cast<short(*)[264]>(&nvb[0][0]);
  #pragma unroll
  for (int fm = 0; fm < 4; ++fm) {
    #pragma unroll
    for (int fn = 0; fn < 4; ++fn) {
      int crow = 64*w + fm*16 + hi*4;
      int tcol = fn*16 + ln15;
      f32x4 u4 = *reinterpret_cast<const f32x4*>(&u[(size_t)(b*64 + tcol)*256 + crow]);
      f32x4 a4 = *reinterpret_cast<const f32x4*>(&a[(size_t)(b*64 + tcol)*256 + crow]);
      #pragma unroll
      for (int j = 0; j < 4; ++j) {
        float g = gelu_f(yacc[fm][fn][j] + s_spb[tcol]);
        float o = u4[j] * (g + a4[j]);
        outl[tcol][crow + j] = f2bf(o);
      }
    }
  }
  __syncthreads();

  #pragma unroll
  for (int ri = 0; ri < 16; ++ri) {
    int trow = w*16 + ri;
    int c = lane * 4;
    s16x4 raw = *reinterpret_cast<const s16x4*>(&outl[trow][c]);
    float f0 = bf2f(raw[0]), f1 = bf2f(raw[1]), f2 = bf2f(raw[2]), f3 = bf2f(raw[3]);
    float s  = f0+f1+f2+f3;
    float sq = f0*f0+f1*f1+f2*f2+f3*f3;
    s = waveSum(s); sq = waveSum(sq);
    float m = s * (1.f/256.f);
    float rstd = rsqrtf(sq * (1.f/256.f) - m*m + 1e-5f);
    s16x4 o;
    o[0] = f2bf((f0-m)*rstd*s_pog[c+0] + s_pob[c+0]);
    o[1] = f2bf((f1-m)*rstd*s_pog[c+1] + s_pob[c+1]);
    o[2] = f2bf((f2-m)*rstd*s_pog[c+2] + s_pob[c+2]);
    o[3] = f2bf((f3-m)*rstd*s_pog[c+3] + s_pob[c+3]);
    *reinterpret_cast<s16x4*>(&outn[(size_t)(b*64 + trow)*256 + c]) = o;
  }
}

// ---------------------------------------------------------------------------
extern "C" void kernel_launch(void* const* d_in, const int* in_sizes, int n_in,
                              void* d_out, int out_size, void* d_ws, size_t ws_size,
                              hipStream_t stream)
{
  const float* x          = (const float*)d_in[0];
  const float* qkv_ln_g   = (const float*)d_in[1];
  const float* qkv_ln_b   = (const float*)d_in[2];
  const float* qkv_w      = (const float*)d_in[3];
  const float* qkv_b      = (const float*)d_in[4];
  const float* attn_pw    = (const float*)d_in[5];
  const float* attn_pb    = (const float*)d_in[6];
  const float* attn_ln_g  = (const float*)d_in[7];
  const float* attn_ln_b  = (const float*)d_in[8];
  const float* rel_bias   = (const float*)d_in[9];
  const float* scale      = (const float*)d_in[10];
  const float* pin_ln_g   = (const float*)d_in[11];
  const float* pin_ln_b   = (const float*)d_in[12];
  const float* pin_w      = (const float*)d_in[13];
  const float* pin_b      = (const float*)d_in[14];
  const float* sp_ln_g    = (const float*)d_in[15];
  const float* sp_ln_b    = (const float*)d_in[16];
  const float* sp_w       = (const float*)d_in[17];
  const float* sp_b       = (const float*)d_in[18];
  const float* pout_ln_g  = (const float*)d_in[19];
  const float* pout_ln_b  = (const float*)d_in[20];
  const float* pout_w     = (const float*)d_in[21];
  const float* pout_b     = (const float*)d_in[22];
  const float* mlp_ln_g   = (const float*)d_in[23];
  const float* mlp_ln_b   = (const float*)d_in[24];
  const float* mlp_w1     = (const float*)d_in[25];
  const float* mlp_b1     = (const float*)d_in[26];
  const float* mlp_w2     = (const float*)d_in[27];
  const float* mlp_b2     = (const float*)d_in[28];

  char* ws = (char*)d_ws;
  short* lnp   = (short*)(ws + 0);           // 8.39 MB (dead after pin gemm)
  float* x1b   = (float*)(ws + 0);           // 16.78 MB (written at pout)
  float* ab    = (float*)(ws + 16777216);    // 33.55 MB f32
  float* ub    = (float*)(ws + 50331648);    // 33.55 MB f32
  short* wTg   = (short*)(ws + 83886080);    // 393 KB (vbf region, pre-pin)
  short* pwTg  = (short*)(ws + 84279296);    // 262 KB
  short* vbfb  = (short*)(ws + 83886080);    // 16.78 MB bf16 (after fused)
  short* outnb = (short*)(ws + 100663296);   // 16.78 MB bf16
  short* lnxp  = (short*)(ws + 150994944);   // 8.39 MB (tile-packed)
  short* h3p   = (short*)(ws + 159383552);   // 9.31 MB (tile-packed)
  float* partb = (float*)(ws + 16777216);    // split-K partials (<=74.5 MB)

  // weight transpose (once) -> wTg, pwTg
  prep_w_k<<<160, 256, 0, stream>>>(qkv_w, attn_pw, wTg, pwTg);
  // fused: LN + qkv + attention + proj + ln256  ->  lnp, ab
  fused_attn_k<<<512, 256, 0, stream>>>(
      x, qkv_ln_g, qkv_ln_b, pin_ln_g, pin_ln_b, wTg, qkv_b,
      pwTg, attn_pb, attn_ln_g, attn_ln_b, rel_bias, scale, lnp, ab);
  // pin: [32768,128]@[128,512]+b, gelu, split u (f32) / v (bf16)
  gemm_k<128,128,2,2,2><<<dim3(4,256), 256, 0, stream>>>(
      lnp, pin_w, pin_b, nullptr, ub, vbfb, 32768, 512, 128, 512, 128);
  // SGU gate + fused pout_ln -> outn bf16
  gate_k<<<512, 256, 0, stream>>>(ub, vbfb, ab, sp_ln_g, sp_ln_b, sp_w, sp_b,
                                  pout_ln_g, pout_ln_b, outnb);
  // pout: [32768,256]@[256,128]+b + x residual -> x1 f32
  gemm_k<128,128,2,2,3><<<dim3(1,256), 256, 0, stream>>>(
      outnb, pout_w, pout_b, x, x1b, nullptr, 32768, 128, 256, 128, 256);
  // LN over 8192 -> lnx (tile-packed)
  ln8192_k<<<512, 256, 0, stream>>>(x1b, mlp_ln_g, mlp_ln_b, lnxp);

  // mlp1: [512,8192] @ [8192,9011] (N padded 9088), split-K 3, 213 blocks
  gemm_splitk9<<<213, 512, 0, stream>>>(
      lnxp, mlp_w1, partb, /*N=*/9088, /*K=*/8192, /*Kreal=*/8192,
      /*ldb=*/9011, /*kchunk=*/2752, /*ntiles=*/71);
  reduce_mlp1_k<<<dim3(9, 512), 256, 0, stream>>>(partb, mlp_b1, h3p, 9088, 9011, 512, 3);

  // mlp2: [512,9088] @ [9011,8192], split-K 4, 256 blocks
  gemm_splitk9<<<256, 512, 0, stream>>>(
      h3p, mlp_w2, partb, /*N=*/8192, /*K=*/9088, /*Kreal=*/9011,
      /*ldb=*/8192, /*kchunk=*/2304, /*ntiles=*/64);
  reduce_mlp2_k<<<dim3(8, 512), 256, 0, stream>>>(partb, mlp_b2, x1b, (float*)d_out, 8192, 512, 4);
}